// Round 6
// baseline (1200.855 us; speedup 1.0000x reference)
//
#include <hip/hip_runtime.h>

#define IN_C 128
#define NEG 0.2f
#define GAT_EPS 1e-16f
#define B_N 128            // dst nodes per bucket (dstLocal fits in 7 bits)
#define NB_MAX 1024        // supports N <= 131072
#define TILE 8192          // edges per partition block

// ---------------- Layer 1 GEMM: x[N,128] @ W1[128,64] -> h1[N,64]; a_src1/a_dst1[N,8]
__global__ __launch_bounds__(256) void gemm1_kernel(
    const float* __restrict__ x, const float* __restrict__ W1,
    const float* __restrict__ att_s1, const float* __restrict__ att_d1,
    float* __restrict__ h1, float* __restrict__ a_src1, float* __restrict__ a_dst1,
    int N)
{
    __shared__ float w1s[IN_C * 64];
    __shared__ float xs[4][IN_C];
    int tid = threadIdx.x;
    for (int i = tid; i < IN_C * 64; i += 256) w1s[i] = W1[i];
    int lane = tid & 63, wid = tid >> 6;
    float att_s = att_s1[lane];   // att_src1 [8][8] row-major; lane = head*8+c
    float att_d = att_d1[lane];
    int ngroups = (N + 3) >> 2;
    for (int grp = blockIdx.x; grp < ngroups; grp += gridDim.x) {
        int nbase = grp * 4;
        __syncthreads();
        for (int i = tid; i < 4 * IN_C; i += 256) {
            int nn = nbase + (i >> 7);
            xs[i >> 7][i & 127] = (nn < N) ? x[(size_t)nn * IN_C + (i & 127)] : 0.f;
        }
        __syncthreads();
        int n = nbase + wid;
        const float* xr = xs[wid];
        float acc = 0.f;
        #pragma unroll 8
        for (int c = 0; c < IN_C; ++c)
            acc = fmaf(xr[c], w1s[c * 64 + lane], acc);
        if (n < N) {
            h1[(size_t)n * 64 + lane] = acc;
            float rs = acc * att_s;
            float rd = acc * att_d;
            rs += __shfl_xor(rs, 1); rd += __shfl_xor(rd, 1);
            rs += __shfl_xor(rs, 2); rd += __shfl_xor(rd, 2);
            rs += __shfl_xor(rs, 4); rd += __shfl_xor(rd, 4);
            if ((lane & 7) == 0) {
                a_src1[n * 8 + (lane >> 3)] = rs;
                a_dst1[n * 8 + (lane >> 3)] = rd;
            }
        }
    }
}

// ---------------- bucket histogram (bin = dst >> 7)
__global__ __launch_bounds__(256) void bucket_count_kernel(
    const int* __restrict__ ei, int* __restrict__ bucketCnt, int E, int Etot, int NB)
{
    __shared__ int hist[NB_MAX];
    int t = threadIdx.x;
    for (int i = t; i < NB; i += 256) hist[i] = 0;
    __syncthreads();
    int base = blockIdx.x * TILE;
    for (int k = t; k < TILE; k += 256) {
        int e = base + k;
        if (e < Etot) {
            int dst = (e < E) ? ei[E + e] : (e - E);   // self-loops appended
            atomicAdd(&hist[dst >> 7], 1);
        }
    }
    __syncthreads();
    for (int i = t; i < NB; i += 256)
        if (hist[i]) atomicAdd(&bucketCnt[i], hist[i]);
}

// ---------------- exclusive scan of bucket counts (1 block; NB <= 1024)
__global__ __launch_bounds__(256) void bucket_scan_kernel(
    const int* __restrict__ cnt, int* __restrict__ base, int* __restrict__ cur, int NB)
{
    int t = threadIdx.x;
    int v[4]; int s = 0;
    #pragma unroll
    for (int k = 0; k < 4; ++k) { int i = t * 4 + k; v[k] = (i < NB) ? cnt[i] : 0; s += v[k]; }
    int tsum = s;
    int lane = t & 63, wid = t >> 6;
    for (int off = 1; off < 64; off <<= 1) {
        int u = __shfl_up(s, off);
        if (lane >= off) s += u;
    }
    __shared__ int wsH[4];
    if (lane == 63) wsH[wid] = s;
    __syncthreads();
    int woff = 0;
    for (int w = 0; w < wid; ++w) woff += wsH[w];
    int excl = woff + (s - tsum);
    #pragma unroll
    for (int k = 0; k < 4; ++k) {
        int i = t * 4 + k;
        if (i < NB) {
            base[i] = excl; cur[i] = excl;
            if (i == NB - 1) base[NB] = excl + v[k];
            excl += v[k];
        }
    }
}

// ---------------- partition: bin edges by dst bucket, coalesced-run writes
// packs each edge as (dstLocal<<25)|src  (src < 2^25, dstLocal < 128)
__global__ __launch_bounds__(256) void partition_kernel(
    const int* __restrict__ ei, int* __restrict__ bucketCur,
    unsigned* __restrict__ ebuf, int E, int Etot, int NB)
{
    __shared__ int lcnt[NB_MAX];
    __shared__ int lbase[NB_MAX];
    int t = threadIdx.x;
    for (int i = t; i < NB; i += 256) lcnt[i] = 0;
    __syncthreads();
    int base = blockIdx.x * TILE;
    for (int k = t; k < TILE; k += 256) {
        int e = base + k;
        if (e < Etot) {
            int dst = (e < E) ? ei[E + e] : (e - E);
            atomicAdd(&lcnt[dst >> 7], 1);
        }
    }
    __syncthreads();
    for (int i = t; i < NB; i += 256) {
        int c = lcnt[i];
        lbase[i] = c ? atomicAdd(&bucketCur[i], c) : 0;
    }
    __syncthreads();
    for (int i = t; i < NB; i += 256) lcnt[i] = 0;   // reuse as local rank cursor
    __syncthreads();
    for (int k = t; k < TILE; k += 256) {
        int e = base + k;
        if (e < Etot) {
            int src, dst;
            if (e < E) { src = ei[e]; dst = ei[E + e]; }
            else       { src = dst = e - E; }
            int b = dst >> 7;
            int r = atomicAdd(&lcnt[b], 1);
            ebuf[lbase[b] + r] = ((unsigned)(dst & (B_N - 1)) << 25) | (unsigned)src;
        }
    }
}

// ---------------- Layer 1 aggregation: one block per bucket, LDS accumulation.
// lane = head*8 + channel; all 8 lanes of a head share w.
__global__ __launch_bounds__(256) void agg1_kernel(
    const unsigned* __restrict__ ebuf, const int* __restrict__ bucketBase,
    const float* __restrict__ a_src1, const float* __restrict__ a_dst1,
    const float* __restrict__ h1, const float* __restrict__ b1,
    float* __restrict__ h2, int N)
{
    __shared__ float acc[B_N * 64];   // 32 KB
    __shared__ float wsm[B_N * 8];    // 4 KB
    __shared__ float adl[B_N * 8];    // 4 KB staged a_dst1 for this bucket
    int blk = blockIdx.x, t = threadIdx.x;
    int lane = t & 63, wv = t >> 6;
    int nodebase = blk * B_N;
    for (int i = t; i < B_N * 64; i += 256) acc[i] = 0.f;
    for (int i = t; i < B_N * 8; i += 256) {
        wsm[i] = 0.f;
        int n = nodebase + (i >> 3);
        adl[i] = (n < N) ? a_dst1[n * 8 + (i & 7)] : 0.f;
    }
    __syncthreads();
    int e0 = bucketBase[blk], e1 = bucketBase[blk + 1];
    int h = lane >> 3;
    int p = e0 + wv;
    for (; p + 4 < e1; p += 8) {                      // 2-deep pipeline per wave
        unsigned pk0 = ebuf[p], pk1 = ebuf[p + 4];
        int s0 = pk0 & 0x1FFFFFF, d0 = pk0 >> 25;
        int s1 = pk1 & 0x1FFFFFF, d1 = pk1 >> 25;
        float a0 = a_src1[s0 * 8 + h] + adl[d0 * 8 + h];
        float a1 = a_src1[s1 * 8 + h] + adl[d1 * 8 + h];
        float v0 = h1[(size_t)s0 * 64 + lane];
        float v1 = h1[(size_t)s1 * 64 + lane];
        a0 = (a0 > 0.f) ? a0 : NEG * a0;
        a1 = (a1 > 0.f) ? a1 : NEG * a1;
        float w0 = __expf(a0), w1 = __expf(a1);
        atomicAdd(&acc[d0 * 64 + lane], w0 * v0);
        atomicAdd(&acc[d1 * 64 + lane], w1 * v1);
        if ((lane & 7) == 0) {
            atomicAdd(&wsm[d0 * 8 + h], w0);
            atomicAdd(&wsm[d1 * 8 + h], w1);
        }
    }
    if (p < e1) {
        unsigned pk0 = ebuf[p];
        int s0 = pk0 & 0x1FFFFFF, d0 = pk0 >> 25;
        float a0 = a_src1[s0 * 8 + h] + adl[d0 * 8 + h];
        a0 = (a0 > 0.f) ? a0 : NEG * a0;
        float w0 = __expf(a0);
        atomicAdd(&acc[d0 * 64 + lane], w0 * h1[(size_t)s0 * 64 + lane]);
        if ((lane & 7) == 0) atomicAdd(&wsm[d0 * 8 + h], w0);
    }
    __syncthreads();
    for (int i = t; i < B_N * 64; i += 256) {
        int n = nodebase + (i >> 6);
        if (n < N) {
            int ln = i & 63;
            float v = acc[i] / (wsm[(i >> 6) * 8 + (ln >> 3)] + GAT_EPS) + b1[ln];
            h2[(size_t)n * 64 + ln] = v > 0.f ? v : 0.f;   // fused relu(norm+bias)
        }
    }
}

// ---------------- Layer 2 GEMM: h2[N,64] @ W2[64,16]; a_src2/a_dst2[N]
__global__ __launch_bounds__(256) void gemm2_kernel(
    const float* __restrict__ h2, const float* __restrict__ W2,
    const float* __restrict__ att_s2, const float* __restrict__ att_d2,
    float* __restrict__ h2w, float* __restrict__ a_src2, float* __restrict__ a_dst2,
    int N)
{
    __shared__ float w2s[64 * 16];
    __shared__ float hs[16][64];
    int tid = threadIdx.x;
    for (int i = tid; i < 64 * 16; i += 256) w2s[i] = W2[i];
    int lane = tid & 63, wid = tid >> 6;
    int j = lane & 15, jn = lane >> 4;
    float att_s = att_s2[j], att_d = att_d2[j];
    int ngroups = (N + 15) >> 4;
    for (int grp = blockIdx.x; grp < ngroups; grp += gridDim.x) {
        int nbase = grp * 16;
        __syncthreads();
        for (int i = tid; i < 16 * 64; i += 256) {
            int nn = nbase + (i >> 6);
            hs[i >> 6][i & 63] = (nn < N) ? h2[(size_t)nn * 64 + (i & 63)] : 0.f;
        }
        __syncthreads();
        int local = wid * 4 + jn;
        int n = nbase + local;
        float acc = 0.f;
        #pragma unroll 8
        for (int c = 0; c < 64; ++c)
            acc = fmaf(hs[local][c], w2s[c * 16 + j], acc);
        if (n < N) {
            h2w[n * 16 + j] = acc;
            float rs = acc * att_s, rd = acc * att_d;
            rs += __shfl_xor(rs, 1); rd += __shfl_xor(rd, 1);
            rs += __shfl_xor(rs, 2); rd += __shfl_xor(rd, 2);
            rs += __shfl_xor(rs, 4); rd += __shfl_xor(rd, 4);
            rs += __shfl_xor(rs, 8); rd += __shfl_xor(rd, 8);
            if (j == 0) { a_src2[n] = rs; a_dst2[n] = rd; }
        }
    }
}

// ---------------- Layer 2 aggregation: one block per bucket; 4 edges per wave iter
__global__ __launch_bounds__(256) void agg2_kernel(
    const unsigned* __restrict__ ebuf, const int* __restrict__ bucketBase,
    const float* __restrict__ a_src2, const float* __restrict__ a_dst2,
    const float* __restrict__ h2w, const float* __restrict__ b2,
    float* __restrict__ out, int N)
{
    __shared__ float acc[B_N * 16];   // 8 KB
    __shared__ float wsm[B_N];
    __shared__ float adl[B_N];
    int blk = blockIdx.x, t = threadIdx.x;
    int lane = t & 63, wv = t >> 6;
    int j = lane & 15, eo = lane >> 4;
    int nodebase = blk * B_N;
    for (int i = t; i < B_N * 16; i += 256) acc[i] = 0.f;
    if (t < B_N) {
        wsm[t] = 0.f;
        int n = nodebase + t;
        adl[t] = (n < N) ? a_dst2[n] : 0.f;
    }
    __syncthreads();
    int e0 = bucketBase[blk], e1 = bucketBase[blk + 1];
    for (int pb = e0 + wv * 4; pb < e1; pb += 16) {
        int p = pb + eo;
        if (p < e1) {
            unsigned pk = ebuf[p];
            int s = pk & 0x1FFFFFF, dL = pk >> 25;
            float a = a_src2[s] + adl[dL];
            a = (a > 0.f) ? a : NEG * a;
            float w = __expf(a);
            atomicAdd(&acc[dL * 16 + j], w * h2w[(size_t)s * 16 + j]);
            if (j == 0) atomicAdd(&wsm[dL], w);
        }
    }
    __syncthreads();
    for (int i = t; i < B_N * 16; i += 256) {
        int n = nodebase + (i >> 4);
        if (n < N) {
            float v = acc[i] / (wsm[i >> 4] + GAT_EPS) + b2[i & 15];
            out[(size_t)n * 16 + (i & 15)] = v > 0.f ? v : 0.f;
        }
    }
}

extern "C" void kernel_launch(void* const* d_in, const int* in_sizes, int n_in,
                              void* d_out, int out_size, void* d_ws, size_t ws_size,
                              hipStream_t stream)
{
    const float* x      = (const float*)d_in[0];
    const int*   ei     = (const int*)  d_in[1];   // [2,E] int32
    const float* W1     = (const float*)d_in[2];
    const float* att_s1 = (const float*)d_in[3];
    const float* att_d1 = (const float*)d_in[4];
    const float* b1     = (const float*)d_in[5];
    const float* W2     = (const float*)d_in[6];
    const float* att_s2 = (const float*)d_in[7];
    const float* att_d2 = (const float*)d_in[8];
    const float* b2     = (const float*)d_in[9];
    float* out = (float*)d_out;

    int N = in_sizes[0] / IN_C;
    int E = in_sizes[1] / 2;
    int Etot = E + N;
    int NB = (N + B_N - 1) / B_N;      // 782 for N=100000 (<= NB_MAX)

    // workspace layout: floats then ints (total ~71.7 MB for N=100K, E=1.6M)
    float* ws = (float*)d_ws;
    float* h1     = ws;                        // N*64
    float* h2     = h1     + (size_t)N * 64;   // N*64
    float* a_src1 = h2     + (size_t)N * 64;   // N*8
    float* a_dst1 = a_src1 + (size_t)N * 8;    // N*8
    float* h2w    = a_dst1 + (size_t)N * 8;    // N*16
    float* a_src2 = h2w    + (size_t)N * 16;   // N
    float* a_dst2 = a_src2 + (size_t)N;        // N
    int* bucketCnt  = (int*)(a_dst2 + (size_t)N);      // NB_MAX
    int* bucketBase = bucketCnt  + NB_MAX;             // NB_MAX+1
    int* bucketCur  = bucketBase + NB_MAX + 1;         // NB_MAX
    unsigned* ebuf  = (unsigned*)(bucketCur + NB_MAX); // Etot

    int egrid = (Etot + TILE - 1) / TILE;

    // ---- bucket partition ----
    hipMemsetAsync(bucketCnt, 0, NB_MAX * sizeof(int), stream);
    bucket_count_kernel<<<egrid, 256, 0, stream>>>(ei, bucketCnt, E, Etot, NB);
    bucket_scan_kernel<<<1, 256, 0, stream>>>(bucketCnt, bucketBase, bucketCur, NB);
    partition_kernel<<<egrid, 256, 0, stream>>>(ei, bucketCur, ebuf, E, Etot, NB);

    // ---- layer 1 ----
    gemm1_kernel<<<1024, 256, 0, stream>>>(x, W1, att_s1, att_d1, h1, a_src1, a_dst1, N);
    agg1_kernel<<<NB, 256, 0, stream>>>(ebuf, bucketBase, a_src1, a_dst1, h1, b1, h2, N);

    // ---- layer 2 ----
    gemm2_kernel<<<1024, 256, 0, stream>>>(h2, W2, att_s2, att_d2, h2w, a_src2, a_dst2, N);
    agg2_kernel<<<NB, 256, 0, stream>>>(ebuf, bucketBase, a_src2, a_dst2, h2w, b2, out, N);
}

// Round 7
// 373.477 us; speedup vs baseline: 3.2153x; 3.2153x over previous
//
#include <hip/hip_runtime.h>

#define IN_C 128
#define NEG 0.2f
#define GAT_EPS 1e-16f
#define B_N 128            // dst nodes per bucket (dstLocal fits in 7 bits)
#define NB_MAX 1024        // supports N <= 131072
#define TILE 8192          // edges per partition block

// ---------------- Layer 1 GEMM: x[N,128] @ W1[128,64] -> h1[N,64]; a_src1/a_dst1[N,8]
__global__ __launch_bounds__(256) void gemm1_kernel(
    const float* __restrict__ x, const float* __restrict__ W1,
    const float* __restrict__ att_s1, const float* __restrict__ att_d1,
    float* __restrict__ h1, float* __restrict__ a_src1, float* __restrict__ a_dst1,
    int N)
{
    __shared__ float w1s[IN_C * 64];
    __shared__ float xs[4][IN_C];
    int tid = threadIdx.x;
    for (int i = tid; i < IN_C * 64; i += 256) w1s[i] = W1[i];
    int lane = tid & 63, wid = tid >> 6;
    float att_s = att_s1[lane];   // att_src1 [8][8] row-major; lane = head*8+c
    float att_d = att_d1[lane];
    int ngroups = (N + 3) >> 2;
    for (int grp = blockIdx.x; grp < ngroups; grp += gridDim.x) {
        int nbase = grp * 4;
        __syncthreads();
        for (int i = tid; i < 4 * IN_C; i += 256) {
            int nn = nbase + (i >> 7);
            xs[i >> 7][i & 127] = (nn < N) ? x[(size_t)nn * IN_C + (i & 127)] : 0.f;
        }
        __syncthreads();
        int n = nbase + wid;
        const float* xr = xs[wid];
        float acc = 0.f;
        #pragma unroll 8
        for (int c = 0; c < IN_C; ++c)
            acc = fmaf(xr[c], w1s[c * 64 + lane], acc);
        if (n < N) {
            h1[(size_t)n * 64 + lane] = acc;
            float rs = acc * att_s;
            float rd = acc * att_d;
            rs += __shfl_xor(rs, 1); rd += __shfl_xor(rd, 1);
            rs += __shfl_xor(rs, 2); rd += __shfl_xor(rd, 2);
            rs += __shfl_xor(rs, 4); rd += __shfl_xor(rd, 4);
            if ((lane & 7) == 0) {
                a_src1[n * 8 + (lane >> 3)] = rs;
                a_dst1[n * 8 + (lane >> 3)] = rd;
            }
        }
    }
}

// ---------------- bucket histogram (bin = dst >> 7)
__global__ __launch_bounds__(256) void bucket_count_kernel(
    const int* __restrict__ ei, int* __restrict__ bucketCnt, int E, int Etot, int NB)
{
    __shared__ int hist[NB_MAX];
    int t = threadIdx.x;
    for (int i = t; i < NB; i += 256) hist[i] = 0;
    __syncthreads();
    int base = blockIdx.x * TILE;
    for (int k = t; k < TILE; k += 256) {
        int e = base + k;
        if (e < Etot) {
            int dst = (e < E) ? ei[E + e] : (e - E);   // self-loops appended
            atomicAdd(&hist[dst >> 7], 1);
        }
    }
    __syncthreads();
    for (int i = t; i < NB; i += 256)
        if (hist[i]) atomicAdd(&bucketCnt[i], hist[i]);
}

// ---------------- exclusive scan of bucket counts (1 block; NB <= 1024)
__global__ __launch_bounds__(256) void bucket_scan_kernel(
    const int* __restrict__ cnt, int* __restrict__ base, int* __restrict__ cur,
    int* __restrict__ rowstart, int NB, int N, int Etot)
{
    int t = threadIdx.x;
    int v[4]; int s = 0;
    #pragma unroll
    for (int k = 0; k < 4; ++k) { int i = t * 4 + k; v[k] = (i < NB) ? cnt[i] : 0; s += v[k]; }
    int tsum = s;
    int lane = t & 63, wid = t >> 6;
    for (int off = 1; off < 64; off <<= 1) {
        int u = __shfl_up(s, off);
        if (lane >= off) s += u;
    }
    __shared__ int wsH[4];
    if (lane == 63) wsH[wid] = s;
    __syncthreads();
    int woff = 0;
    for (int w = 0; w < wid; ++w) woff += wsH[w];
    int excl = woff + (s - tsum);
    #pragma unroll
    for (int k = 0; k < 4; ++k) {
        int i = t * 4 + k;
        if (i < NB) {
            base[i] = excl; cur[i] = excl;
            if (i == NB - 1) base[NB] = excl + v[k];
            excl += v[k];
        }
    }
    if (t == 0) rowstart[N] = Etot;
}

// ---------------- partition: bin edges by dst bucket, burst writes per (block,bin)
// packs each edge as (dstLocal<<25)|src  (src < 2^25, dstLocal < 128)
__global__ __launch_bounds__(256) void partition_kernel(
    const int* __restrict__ ei, int* __restrict__ bucketCur,
    unsigned* __restrict__ ebuf, int E, int Etot, int NB)
{
    __shared__ int lcnt[NB_MAX];
    __shared__ int lbase[NB_MAX];
    int t = threadIdx.x;
    for (int i = t; i < NB; i += 256) lcnt[i] = 0;
    __syncthreads();
    int base = blockIdx.x * TILE;
    for (int k = t; k < TILE; k += 256) {
        int e = base + k;
        if (e < Etot) {
            int dst = (e < E) ? ei[E + e] : (e - E);
            atomicAdd(&lcnt[dst >> 7], 1);
        }
    }
    __syncthreads();
    for (int i = t; i < NB; i += 256) {
        int c = lcnt[i];
        lbase[i] = c ? atomicAdd(&bucketCur[i], c) : 0;
    }
    __syncthreads();
    for (int i = t; i < NB; i += 256) lcnt[i] = 0;   // reuse as local rank cursor
    __syncthreads();
    for (int k = t; k < TILE; k += 256) {
        int e = base + k;
        if (e < Etot) {
            int src, dst;
            if (e < E) { src = ei[e]; dst = ei[E + e]; }
            else       { src = dst = e - E; }
            int b = dst >> 7;
            int r = atomicAdd(&lcnt[b], 1);
            ebuf[lbase[b] + r] = ((unsigned)(dst & (B_N - 1)) << 25) | (unsigned)src;
        }
    }
}

// ---------------- per-bucket counting sort: ebuf bucket -> esrc sorted by node,
// and global rowstart[] for the bucket's 128 nodes. Writes stay in the bucket's
// contiguous region -> full cache lines, ~no write amplification.
__global__ __launch_bounds__(256) void bucket_sort_kernel(
    const unsigned* __restrict__ ebuf, const int* __restrict__ bucketBase,
    int* __restrict__ rowstart, int* __restrict__ esrc, int N)
{
    __shared__ int lhist[B_N];
    __shared__ int lstart[B_N];
    __shared__ int wsum1;
    int blk = blockIdx.x, t = threadIdx.x;
    int e0 = bucketBase[blk], e1 = bucketBase[blk + 1];
    if (t < B_N) lhist[t] = 0;
    __syncthreads();
    for (int k = e0 + t; k < e1; k += 256)
        atomicAdd(&lhist[ebuf[k] >> 25], 1);
    __syncthreads();
    int lane = t & 63;
    if (t < B_N) {                       // inclusive scan over 2 waves
        int s = lhist[t];
        for (int off = 1; off < 64; off <<= 1) {
            int u = __shfl_up(s, off);
            if (lane >= off) s += u;
        }
        lstart[t] = s;
        if (t == 63) wsum1 = s;          // total of wave 0
    }
    __syncthreads();
    if (t < B_N) {
        int s = lstart[t];
        if (t >= 64) s += wsum1;
        int excl = s - lhist[t];
        lstart[t] = excl;
        int n = blk * B_N + t;
        if (n < N) rowstart[n] = e0 + excl;
    }
    __syncthreads();
    if (t < B_N) lhist[t] = 0;           // reuse as rank cursor
    __syncthreads();
    for (int k = e0 + t; k < e1; k += 256) {
        unsigned pk = ebuf[k];
        int d = pk >> 25;
        int r = atomicAdd(&lhist[d], 1);
        esrc[e0 + lstart[d] + r] = (int)(pk & 0x1FFFFFF);
    }
}

// ---------------- Layer 1 aggregation: one wave per dst, register accumulation.
// lane = head*8 + channel; all 8 lanes of a head share the same w.
__global__ __launch_bounds__(256) void agg1_kernel(
    const int* __restrict__ esrc, const int* __restrict__ rowstart,
    const float* __restrict__ a_src1, const float* __restrict__ a_dst1,
    const float* __restrict__ h1, const float* __restrict__ b1,
    float* __restrict__ h2, int N)
{
    int wglobal = (blockIdx.x * 256 + threadIdx.x) >> 6;
    int nwaves = (gridDim.x * 256) >> 6;
    int lane = threadIdx.x & 63;
    int h = lane >> 3;
    float bj = b1[lane];
    for (int n = wglobal; n < N; n += nwaves) {
        int p = rowstart[n], end = rowstart[n + 1];
        float ad = a_dst1[n * 8 + h];
        float acc = 0.f, wsum = 0.f;
        for (; p + 1 < end; p += 2) {            // 2-deep to break the load chain
            int s0 = esrc[p], s1 = esrc[p + 1];
            float a0 = a_src1[s0 * 8 + h] + ad;
            float a1 = a_src1[s1 * 8 + h] + ad;
            a0 = (a0 > 0.f) ? a0 : NEG * a0;
            a1 = (a1 > 0.f) ? a1 : NEG * a1;
            float w0 = __expf(a0), w1 = __expf(a1);
            float v0 = h1[(size_t)s0 * 64 + lane];
            float v1 = h1[(size_t)s1 * 64 + lane];
            acc = fmaf(w0, v0, acc);
            acc = fmaf(w1, v1, acc);
            wsum += w0 + w1;
        }
        if (p < end) {
            int s0 = esrc[p];
            float a0 = a_src1[s0 * 8 + h] + ad;
            a0 = (a0 > 0.f) ? a0 : NEG * a0;
            float w0 = __expf(a0);
            acc = fmaf(w0, h1[(size_t)s0 * 64 + lane], acc);
            wsum += w0;
        }
        float v = acc / (wsum + GAT_EPS) + bj;
        h2[(size_t)n * 64 + lane] = v > 0.f ? v : 0.f;   // fused relu(norm + bias)
    }
}

// ---------------- Layer 2 GEMM: h2[N,64] @ W2[64,16]; a_src2/a_dst2[N]
__global__ __launch_bounds__(256) void gemm2_kernel(
    const float* __restrict__ h2, const float* __restrict__ W2,
    const float* __restrict__ att_s2, const float* __restrict__ att_d2,
    float* __restrict__ h2w, float* __restrict__ a_src2, float* __restrict__ a_dst2,
    int N)
{
    __shared__ float w2s[64 * 16];
    __shared__ float hs[16][64];
    int tid = threadIdx.x;
    for (int i = tid; i < 64 * 16; i += 256) w2s[i] = W2[i];
    int lane = tid & 63, wid = tid >> 6;
    int j = lane & 15, jn = lane >> 4;
    float att_s = att_s2[j], att_d = att_d2[j];
    int ngroups = (N + 15) >> 4;
    for (int grp = blockIdx.x; grp < ngroups; grp += gridDim.x) {
        int nbase = grp * 16;
        __syncthreads();
        for (int i = tid; i < 16 * 64; i += 256) {
            int nn = nbase + (i >> 6);
            hs[i >> 6][i & 63] = (nn < N) ? h2[(size_t)nn * 64 + (i & 63)] : 0.f;
        }
        __syncthreads();
        int local = wid * 4 + jn;
        int n = nbase + local;
        float acc = 0.f;
        #pragma unroll 8
        for (int c = 0; c < 64; ++c)
            acc = fmaf(hs[local][c], w2s[c * 16 + j], acc);
        if (n < N) {
            h2w[n * 16 + j] = acc;
            float rs = acc * att_s, rd = acc * att_d;
            rs += __shfl_xor(rs, 1); rd += __shfl_xor(rd, 1);
            rs += __shfl_xor(rs, 2); rd += __shfl_xor(rd, 2);
            rs += __shfl_xor(rs, 4); rd += __shfl_xor(rd, 4);
            rs += __shfl_xor(rs, 8); rd += __shfl_xor(rd, 8);
            if (j == 0) { a_src2[n] = rs; a_dst2[n] = rd; }
        }
    }
}

// ---------------- Layer 2 aggregation: one wave per dst; 4 edges in flight
// (lane = eo*16 + j); all 16 lanes of an eo-group share w.
__global__ __launch_bounds__(256) void agg2_kernel(
    const int* __restrict__ esrc, const int* __restrict__ rowstart,
    const float* __restrict__ a_src2, const float* __restrict__ a_dst2,
    const float* __restrict__ h2w, const float* __restrict__ b2,
    float* __restrict__ out, int N)
{
    int wglobal = (blockIdx.x * 256 + threadIdx.x) >> 6;
    int nwaves = (gridDim.x * 256) >> 6;
    int lane = threadIdx.x & 63;
    int j = lane & 15, eo = lane >> 4;
    float bj = b2[j];
    for (int n = wglobal; n < N; n += nwaves) {
        int start = rowstart[n], end = rowstart[n + 1];
        float ad = a_dst2[n];
        float acc = 0.f, wsum = 0.f;
        for (int p = start + eo; p < end; p += 4) {
            int s = esrc[p];
            float a = a_src2[s] + ad;
            a = (a > 0.f) ? a : NEG * a;
            float w = __expf(a);
            acc = fmaf(w, h2w[(size_t)s * 16 + j], acc);
            wsum += w;
        }
        acc += __shfl_xor(acc, 16); wsum += __shfl_xor(wsum, 16);
        acc += __shfl_xor(acc, 32); wsum += __shfl_xor(wsum, 32);
        if (eo == 0) {
            float v = acc / (wsum + GAT_EPS) + bj;
            out[(size_t)n * 16 + j] = v > 0.f ? v : 0.f;
        }
    }
}

extern "C" void kernel_launch(void* const* d_in, const int* in_sizes, int n_in,
                              void* d_out, int out_size, void* d_ws, size_t ws_size,
                              hipStream_t stream)
{
    const float* x      = (const float*)d_in[0];
    const int*   ei     = (const int*)  d_in[1];   // [2,E] int32
    const float* W1     = (const float*)d_in[2];
    const float* att_s1 = (const float*)d_in[3];
    const float* att_d1 = (const float*)d_in[4];
    const float* b1     = (const float*)d_in[5];
    const float* W2     = (const float*)d_in[6];
    const float* att_s2 = (const float*)d_in[7];
    const float* att_d2 = (const float*)d_in[8];
    const float* b2     = (const float*)d_in[9];
    float* out = (float*)d_out;

    int N = in_sizes[0] / IN_C;
    int E = in_sizes[1] / 2;
    int Etot = E + N;
    int NB = (N + B_N - 1) / B_N;      // 782 for N=100000 (<= NB_MAX)

    // workspace: floats, then ints. ebuf (transient) aliases h2w/a_src2/a_dst2
    // (N*18 floats >= Etot ints), which gemm2 writes only AFTER bucket_sort.
    float* ws = (float*)d_ws;
    float* h1     = ws;                        // N*64
    float* h2     = h1     + (size_t)N * 64;   // N*64
    float* a_src1 = h2     + (size_t)N * 64;   // N*8
    float* a_dst1 = a_src1 + (size_t)N * 8;    // N*8
    float* h2w    = a_dst1 + (size_t)N * 8;    // N*16
    float* a_src2 = h2w    + (size_t)N * 16;   // N
    float* a_dst2 = a_src2 + (size_t)N;        // N
    int* rowstart   = (int*)(a_dst2 + (size_t)N);      // N+1
    int* bucketCnt  = rowstart   + (N + 1);            // NB_MAX
    int* bucketBase = bucketCnt  + NB_MAX;             // NB_MAX+1
    int* bucketCur  = bucketBase + NB_MAX + 1;         // NB_MAX
    int* esrc       = bucketCur  + NB_MAX;             // Etot
    unsigned* ebuf  = (unsigned*)h2w;                  // Etot (transient alias)

    int egrid = (Etot + TILE - 1) / TILE;

    // ---- CSR build: bucket partition + per-bucket counting sort ----
    hipMemsetAsync(bucketCnt, 0, NB_MAX * sizeof(int), stream);
    bucket_count_kernel<<<egrid, 256, 0, stream>>>(ei, bucketCnt, E, Etot, NB);
    bucket_scan_kernel<<<1, 256, 0, stream>>>(bucketCnt, bucketBase, bucketCur,
                                              rowstart, NB, N, Etot);
    partition_kernel<<<egrid, 256, 0, stream>>>(ei, bucketCur, ebuf, E, Etot, NB);
    bucket_sort_kernel<<<NB, 256, 0, stream>>>(ebuf, bucketBase, rowstart, esrc, N);

    // ---- layer 1 ----
    gemm1_kernel<<<1024, 256, 0, stream>>>(x, W1, att_s1, att_d1, h1, a_src1, a_dst1, N);
    agg1_kernel<<<2048, 256, 0, stream>>>(esrc, rowstart, a_src1, a_dst1, h1, b1, h2, N);

    // ---- layer 2 ----
    gemm2_kernel<<<1024, 256, 0, stream>>>(h2, W2, att_s2, att_d2, h2w, a_src2, a_dst2, N);
    agg2_kernel<<<1024, 256, 0, stream>>>(esrc, rowstart, a_src2, a_dst2, h2w, b2, out, N);
}

// Round 8
// 313.347 us; speedup vs baseline: 3.8324x; 1.1919x over previous
//
#include <hip/hip_runtime.h>
#include <hip/hip_fp16.h>

#define IN_C 128
#define NEG 0.2f
#define GAT_EPS 1e-16f
#define B_N 128            // dst nodes per bucket (dstLocal fits in 7 bits)
#define NB_MAX 1024        // supports N <= 131072
#define TILE 8192          // edges per partition block

// ---------------- Layer 1 GEMM: x[N,128] @ W1[128,64] -> packed hp rows
// hp row (192 B, float stride 48): [0:128)B = 64 fp16 h values, [128:160)B = 8 fp32 a_src, pad.
__global__ __launch_bounds__(256) void gemm1_kernel(
    const float* __restrict__ x, const float* __restrict__ W1,
    const float* __restrict__ att_s1, const float* __restrict__ att_d1,
    float* __restrict__ hp, float* __restrict__ a_dst1, int N)
{
    __shared__ float w1s[IN_C * 64];
    __shared__ float xs[4][IN_C];
    int tid = threadIdx.x;
    for (int i = tid; i < IN_C * 64; i += 256) w1s[i] = W1[i];
    int lane = tid & 63, wid = tid >> 6;
    float att_s = att_s1[lane];   // att_src1 [8][8] row-major; lane = head*8+c
    float att_d = att_d1[lane];
    int ngroups = (N + 3) >> 2;
    for (int grp = blockIdx.x; grp < ngroups; grp += gridDim.x) {
        int nbase = grp * 4;
        __syncthreads();
        for (int i = tid; i < 4 * IN_C; i += 256) {
            int nn = nbase + (i >> 7);
            xs[i >> 7][i & 127] = (nn < N) ? x[(size_t)nn * IN_C + (i & 127)] : 0.f;
        }
        __syncthreads();
        int n = nbase + wid;
        const float* xr = xs[wid];
        float acc = 0.f;
        #pragma unroll 8
        for (int c = 0; c < IN_C; ++c)
            acc = fmaf(xr[c], w1s[c * 64 + lane], acc);
        if (n < N) {
            __half* hrow = (__half*)(hp + (size_t)n * 48);
            hrow[lane] = __float2half(acc);
            float rs = acc * att_s;
            float rd = acc * att_d;
            rs += __shfl_xor(rs, 1); rd += __shfl_xor(rd, 1);
            rs += __shfl_xor(rs, 2); rd += __shfl_xor(rd, 2);
            rs += __shfl_xor(rs, 4); rd += __shfl_xor(rd, 4);
            if ((lane & 7) == 0) {
                hp[(size_t)n * 48 + 32 + (lane >> 3)] = rs;   // a_src packed
                a_dst1[n * 8 + (lane >> 3)] = rd;
            }
        }
    }
}

// ---------------- bucket histogram (bin = dst >> 7)
__global__ __launch_bounds__(256) void bucket_count_kernel(
    const int* __restrict__ ei, int* __restrict__ bucketCnt, int E, int Etot, int NB)
{
    __shared__ int hist[NB_MAX];
    int t = threadIdx.x;
    for (int i = t; i < NB; i += 256) hist[i] = 0;
    __syncthreads();
    int base = blockIdx.x * TILE;
    for (int k = t; k < TILE; k += 256) {
        int e = base + k;
        if (e < Etot) {
            int dst = (e < E) ? ei[E + e] : (e - E);   // self-loops appended
            atomicAdd(&hist[dst >> 7], 1);
        }
    }
    __syncthreads();
    for (int i = t; i < NB; i += 256)
        if (hist[i]) atomicAdd(&bucketCnt[i], hist[i]);
}

// ---------------- exclusive scan of bucket counts (1 block; NB <= 1024)
__global__ __launch_bounds__(256) void bucket_scan_kernel(
    const int* __restrict__ cnt, int* __restrict__ base, int* __restrict__ cur,
    int* __restrict__ rowstart, int NB, int N, int Etot)
{
    int t = threadIdx.x;
    int v[4]; int s = 0;
    #pragma unroll
    for (int k = 0; k < 4; ++k) { int i = t * 4 + k; v[k] = (i < NB) ? cnt[i] : 0; s += v[k]; }
    int tsum = s;
    int lane = t & 63, wid = t >> 6;
    for (int off = 1; off < 64; off <<= 1) {
        int u = __shfl_up(s, off);
        if (lane >= off) s += u;
    }
    __shared__ int wsH[4];
    if (lane == 63) wsH[wid] = s;
    __syncthreads();
    int woff = 0;
    for (int w = 0; w < wid; ++w) woff += wsH[w];
    int excl = woff + (s - tsum);
    #pragma unroll
    for (int k = 0; k < 4; ++k) {
        int i = t * 4 + k;
        if (i < NB) {
            base[i] = excl; cur[i] = excl;
            if (i == NB - 1) base[NB] = excl + v[k];
            excl += v[k];
        }
    }
    if (t == 0) rowstart[N] = Etot;
}

// ---------------- partition: bin edges by dst bucket, burst writes per (block,bin)
// packs each edge as (dstLocal<<25)|src  (src < 2^25, dstLocal < 128)
__global__ __launch_bounds__(256) void partition_kernel(
    const int* __restrict__ ei, int* __restrict__ bucketCur,
    unsigned* __restrict__ ebuf, int E, int Etot, int NB)
{
    __shared__ int lcnt[NB_MAX];
    __shared__ int lbase[NB_MAX];
    int t = threadIdx.x;
    for (int i = t; i < NB; i += 256) lcnt[i] = 0;
    __syncthreads();
    int base = blockIdx.x * TILE;
    for (int k = t; k < TILE; k += 256) {
        int e = base + k;
        if (e < Etot) {
            int dst = (e < E) ? ei[E + e] : (e - E);
            atomicAdd(&lcnt[dst >> 7], 1);
        }
    }
    __syncthreads();
    for (int i = t; i < NB; i += 256) {
        int c = lcnt[i];
        lbase[i] = c ? atomicAdd(&bucketCur[i], c) : 0;
    }
    __syncthreads();
    for (int i = t; i < NB; i += 256) lcnt[i] = 0;   // reuse as local rank cursor
    __syncthreads();
    for (int k = t; k < TILE; k += 256) {
        int e = base + k;
        if (e < Etot) {
            int src, dst;
            if (e < E) { src = ei[e]; dst = ei[E + e]; }
            else       { src = dst = e - E; }
            int b = dst >> 7;
            int r = atomicAdd(&lcnt[b], 1);
            ebuf[lbase[b] + r] = ((unsigned)(dst & (B_N - 1)) << 25) | (unsigned)src;
        }
    }
}

// ---------------- per-bucket counting sort -> esrc sorted by node + rowstart
__global__ __launch_bounds__(256) void bucket_sort_kernel(
    const unsigned* __restrict__ ebuf, const int* __restrict__ bucketBase,
    int* __restrict__ rowstart, int* __restrict__ esrc, int N)
{
    __shared__ int lhist[B_N];
    __shared__ int lstart[B_N];
    __shared__ int wsum1;
    int blk = blockIdx.x, t = threadIdx.x;
    int e0 = bucketBase[blk], e1 = bucketBase[blk + 1];
    if (t < B_N) lhist[t] = 0;
    __syncthreads();
    for (int k = e0 + t; k < e1; k += 256)
        atomicAdd(&lhist[ebuf[k] >> 25], 1);
    __syncthreads();
    int lane = t & 63;
    if (t < B_N) {                       // inclusive scan over 2 waves
        int s = lhist[t];
        for (int off = 1; off < 64; off <<= 1) {
            int u = __shfl_up(s, off);
            if (lane >= off) s += u;
        }
        lstart[t] = s;
        if (t == 63) wsum1 = s;          // total of wave 0
    }
    __syncthreads();
    if (t < B_N) {
        int s = lstart[t];
        if (t >= 64) s += wsum1;
        int excl = s - lhist[t];
        lstart[t] = excl;
        int n = blk * B_N + t;
        if (n < N) rowstart[n] = e0 + excl;
    }
    __syncthreads();
    if (t < B_N) lhist[t] = 0;           // reuse as rank cursor
    __syncthreads();
    for (int k = e0 + t; k < e1; k += 256) {
        unsigned pk = ebuf[k];
        int d = pk >> 25;
        int r = atomicAdd(&lhist[d], 1);
        esrc[e0 + lstart[d] + r] = (int)(pk & 0x1FFFFFF);
    }
}

// ---------------- Layer 1 aggregation: wave per dst; lane = eo*32+c2 handles
// channels {2c2,2c2+1} of edge-parity eo. 2 edges/iter + 2-deep unroll.
__global__ __launch_bounds__(256) void agg1_kernel(
    const int* __restrict__ esrc, const int* __restrict__ rowstart,
    const float* __restrict__ hp, const float* __restrict__ a_dst1,
    const float* __restrict__ b1, __half* __restrict__ h2, int N)
{
    int wglobal = (blockIdx.x * 256 + threadIdx.x) >> 6;
    int nwaves = (gridDim.x * 256) >> 6;
    int lane = threadIdx.x & 63;
    int c2 = lane & 31, eo = lane >> 5;
    int h = c2 >> 2;                      // head of channels 2c2,2c2+1
    for (int n = wglobal; n < N; n += nwaves) {
        int end = rowstart[n + 1];
        float ad = a_dst1[n * 8 + h];
        float ax = 0.f, ay = 0.f, wsum = 0.f;
        int p = rowstart[n] + eo;
        for (; p + 2 < end; p += 4) {
            int s0 = esrc[p], s1 = esrc[p + 2];
            const float* r0 = hp + (size_t)s0 * 48;
            const float* r1 = hp + (size_t)s1 * 48;
            float a0 = r0[32 + h] + ad;
            float a1 = r1[32 + h] + ad;
            __half2 q0 = ((const __half2*)r0)[c2];
            __half2 q1 = ((const __half2*)r1)[c2];
            a0 = (a0 > 0.f) ? a0 : NEG * a0;
            a1 = (a1 > 0.f) ? a1 : NEG * a1;
            float w0 = __expf(a0), w1 = __expf(a1);
            ax = fmaf(w0, __low2float(q0), ax);
            ay = fmaf(w0, __high2float(q0), ay);
            ax = fmaf(w1, __low2float(q1), ax);
            ay = fmaf(w1, __high2float(q1), ay);
            wsum += w0 + w1;
        }
        if (p < end) {
            int s0 = esrc[p];
            const float* r0 = hp + (size_t)s0 * 48;
            float a0 = r0[32 + h] + ad;
            __half2 q0 = ((const __half2*)r0)[c2];
            a0 = (a0 > 0.f) ? a0 : NEG * a0;
            float w0 = __expf(a0);
            ax = fmaf(w0, __low2float(q0), ax);
            ay = fmaf(w0, __high2float(q0), ay);
            wsum += w0;
        }
        ax += __shfl_xor(ax, 32);
        ay += __shfl_xor(ay, 32);
        wsum += __shfl_xor(wsum, 32);
        if (eo == 0) {
            float inv = 1.f / (wsum + GAT_EPS);
            float2 bb = *(const float2*)(b1 + 2 * c2);
            float vx = fmaf(ax, inv, bb.x);
            float vy = fmaf(ay, inv, bb.y);
            vx = vx > 0.f ? vx : 0.f;
            vy = vy > 0.f ? vy : 0.f;
            ((__half2*)(h2 + (size_t)n * 64))[c2] =
                __halves2half2(__float2half(vx), __float2half(vy));
        }
    }
}

// ---------------- Layer 2 GEMM: h2(fp16)[N,64] @ W2[64,16] -> packed h2w rows
// h2w row (64 B, float stride 16): [0:32)B = 16 fp16, [32:36)B = fp32 a_src2, pad.
__global__ __launch_bounds__(256) void gemm2_kernel(
    const __half* __restrict__ h2, const float* __restrict__ W2,
    const float* __restrict__ att_s2, const float* __restrict__ att_d2,
    float* __restrict__ h2w, float* __restrict__ a_dst2, int N)
{
    __shared__ float w2s[64 * 16];
    __shared__ float hs[16][64];
    int tid = threadIdx.x;
    for (int i = tid; i < 64 * 16; i += 256) w2s[i] = W2[i];
    int lane = tid & 63, wid = tid >> 6;
    int j = lane & 15, jn = lane >> 4;
    float att_s = att_s2[j], att_d = att_d2[j];
    int ngroups = (N + 15) >> 4;
    for (int grp = blockIdx.x; grp < ngroups; grp += gridDim.x) {
        int nbase = grp * 16;
        __syncthreads();
        for (int i = tid; i < 16 * 32; i += 256) {     // 512 half2 loads
            int rr = i >> 5, cc = i & 31;
            int nn = nbase + rr;
            float lo = 0.f, hi = 0.f;
            if (nn < N) {
                __half2 q = ((const __half2*)(h2 + (size_t)nn * 64))[cc];
                lo = __low2float(q); hi = __high2float(q);
            }
            hs[rr][cc * 2] = lo; hs[rr][cc * 2 + 1] = hi;
        }
        __syncthreads();
        int local = wid * 4 + jn;
        int n = nbase + local;
        float acc = 0.f;
        #pragma unroll 8
        for (int c = 0; c < 64; ++c)
            acc = fmaf(hs[local][c], w2s[c * 16 + j], acc);
        if (n < N) {
            float* row = h2w + (size_t)n * 16;
            ((__half*)row)[j] = __float2half(acc);
            float rs = acc * att_s, rd = acc * att_d;
            rs += __shfl_xor(rs, 1); rd += __shfl_xor(rd, 1);
            rs += __shfl_xor(rs, 2); rd += __shfl_xor(rd, 2);
            rs += __shfl_xor(rs, 4); rd += __shfl_xor(rd, 4);
            rs += __shfl_xor(rs, 8); rd += __shfl_xor(rd, 8);
            if (j == 0) { row[8] = rs; a_dst2[n] = rd; }
        }
    }
}

// ---------------- Layer 2 aggregation: wave per dst; lane = eo*8+c2, 8 edges/iter
__global__ __launch_bounds__(256) void agg2_kernel(
    const int* __restrict__ esrc, const int* __restrict__ rowstart,
    const float* __restrict__ h2w, const float* __restrict__ a_dst2,
    const float* __restrict__ b2, float* __restrict__ out, int N)
{
    int wglobal = (blockIdx.x * 256 + threadIdx.x) >> 6;
    int nwaves = (gridDim.x * 256) >> 6;
    int lane = threadIdx.x & 63;
    int c2 = lane & 7, eo = lane >> 3;
    for (int n = wglobal; n < N; n += nwaves) {
        int start = rowstart[n], end = rowstart[n + 1];
        float ad = a_dst2[n];
        float ax = 0.f, ay = 0.f, wsum = 0.f;
        for (int p = start + eo; p < end; p += 8) {
            int s = esrc[p];
            const float* r = h2w + (size_t)s * 16;
            float a = r[8] + ad;
            __half2 q = ((const __half2*)r)[c2];
            a = (a > 0.f) ? a : NEG * a;
            float w = __expf(a);
            ax = fmaf(w, __low2float(q), ax);
            ay = fmaf(w, __high2float(q), ay);
            wsum += w;
        }
        ax += __shfl_xor(ax, 8);  ay += __shfl_xor(ay, 8);  wsum += __shfl_xor(wsum, 8);
        ax += __shfl_xor(ax, 16); ay += __shfl_xor(ay, 16); wsum += __shfl_xor(wsum, 16);
        ax += __shfl_xor(ax, 32); ay += __shfl_xor(ay, 32); wsum += __shfl_xor(wsum, 32);
        if (eo == 0) {
            float inv = 1.f / (wsum + GAT_EPS);
            float2 bb = *(const float2*)(b2 + 2 * c2);
            float2 o;
            o.x = fmaf(ax, inv, bb.x);
            o.y = fmaf(ay, inv, bb.y);
            o.x = o.x > 0.f ? o.x : 0.f;
            o.y = o.y > 0.f ? o.y : 0.f;
            ((float2*)(out + (size_t)n * 16))[c2] = o;
        }
    }
}

extern "C" void kernel_launch(void* const* d_in, const int* in_sizes, int n_in,
                              void* d_out, int out_size, void* d_ws, size_t ws_size,
                              hipStream_t stream)
{
    const float* x      = (const float*)d_in[0];
    const int*   ei     = (const int*)  d_in[1];   // [2,E] int32
    const float* W1     = (const float*)d_in[2];
    const float* att_s1 = (const float*)d_in[3];
    const float* att_d1 = (const float*)d_in[4];
    const float* b1     = (const float*)d_in[5];
    const float* W2     = (const float*)d_in[6];
    const float* att_s2 = (const float*)d_in[7];
    const float* att_d2 = (const float*)d_in[8];
    const float* b2     = (const float*)d_in[9];
    float* out = (float*)d_out;

    int N = in_sizes[0] / IN_C;
    int E = in_sizes[1] / 2;
    int Etot = E + N;
    int NB = (N + B_N - 1) / B_N;      // 782 for N=100000 (<= NB_MAX)

    // workspace: floats, then ints. ebuf (transient, pre-gemm1) aliases hp.
    float* ws = (float*)d_ws;
    float*  hp     = ws;                          // N*48 (packed fp16 h + fp32 a_src1)
    __half* h2     = (__half*)(hp + (size_t)N * 48);   // N*64 halves = N*32 floats
    float*  a_dst1 = (float*)h2 + (size_t)N * 32 - (size_t)0;  // see below
    a_dst1 = ((float*)h2) + (size_t)N * 32;       // N*8
    float*  h2w    = a_dst1 + (size_t)N * 8;      // N*16 (packed fp16 + a_src2)
    float*  a_dst2 = h2w    + (size_t)N * 16;     // N
    int* rowstart   = (int*)(a_dst2 + (size_t)N); // N+1
    int* bucketCnt  = rowstart   + (N + 1);       // NB_MAX
    int* bucketBase = bucketCnt  + NB_MAX;        // NB_MAX+1
    int* bucketCur  = bucketBase + NB_MAX + 1;    // NB_MAX
    int* esrc       = bucketCur  + NB_MAX;        // Etot
    unsigned* ebuf  = (unsigned*)hp;              // Etot ints <= N*48 floats (transient)

    int egrid = (Etot + TILE - 1) / TILE;

    // ---- CSR build: bucket partition + per-bucket counting sort ----
    hipMemsetAsync(bucketCnt, 0, NB_MAX * sizeof(int), stream);
    bucket_count_kernel<<<egrid, 256, 0, stream>>>(ei, bucketCnt, E, Etot, NB);
    bucket_scan_kernel<<<1, 256, 0, stream>>>(bucketCnt, bucketBase, bucketCur,
                                              rowstart, NB, N, Etot);
    partition_kernel<<<egrid, 256, 0, stream>>>(ei, bucketCur, ebuf, E, Etot, NB);
    bucket_sort_kernel<<<NB, 256, 0, stream>>>(ebuf, bucketBase, rowstart, esrc, N);

    // ---- layer 1 ----
    gemm1_kernel<<<1024, 256, 0, stream>>>(x, W1, att_s1, att_d1, hp, a_dst1, N);
    agg1_kernel<<<2048, 256, 0, stream>>>(esrc, rowstart, hp, a_dst1, b1, h2, N);

    // ---- layer 2 ----
    gemm2_kernel<<<1024, 256, 0, stream>>>(h2, W2, att_s2, att_d2, h2w, a_dst2, N);
    agg2_kernel<<<1024, 256, 0, stream>>>(esrc, rowstart, h2w, a_dst2, b2, out, N);
}

// Round 9
// 239.449 us; speedup vs baseline: 5.0151x; 1.3086x over previous
//
#include <hip/hip_runtime.h>
#include <hip/hip_fp16.h>

#define IN_C 128
#define NEG 0.2f
#define GAT_EPS 1e-16f
#define B_N 128            // dst nodes per bucket (dstLocal fits in 7 bits)
#define NB_MAX 1024        // supports N <= 131072
#define TILE 8192          // edges per partition block

typedef _Float16 half8 __attribute__((ext_vector_type(8)));
typedef float f32x4 __attribute__((ext_vector_type(4)));

static __device__ inline unsigned short f2h(float f) {
    _Float16 h = (_Float16)f;
    unsigned short u;
    __builtin_memcpy(&u, &h, 2);
    return u;
}

// ---------------- Layer 1 GEMM (MFMA): x[N,128](fp16) @ W1[128,64](fp16) -> packed hp rows
// hp row (192 B, float stride 48): [0:128)B = 64 fp16 h, [128:160)B = 8 fp32 a_src, pad.
// One wave computes one 16-node tile: 4 K-chunks x 4 N-tiles of 16x16x32 MFMA.
__global__ __launch_bounds__(256) void gemm1_kernel(
    const float* __restrict__ x, const float* __restrict__ W1,
    const float* __restrict__ att_s1, const float* __restrict__ att_d1,
    float* __restrict__ hp, float* __restrict__ a_dst1, int N)
{
    __shared__ _Float16 bfrag[16 * 512];   // 16 KB: frag f, lane l, elem j at f*512+l*8+j
    __shared__ float cs[4][16 * 68];       // 17.4 KB: per-wave C staging, padded stride 68
    __shared__ float attS[64], attD[64];
    int tid = threadIdx.x;
    if (tid < 64) { attS[tid] = att_s1[tid]; attD[tid] = att_d1[tid]; }
    // Build W1 fragments: frag f=(k0*4+nt); lane holds B[k0*32+(l>>4)*8+j][nt*16+(l&15)].
    // (k-map must only match the A-pack's k-map — any consistent bijection is correct.)
    for (int idx = tid; idx < 8192; idx += 256) {
        int f = idx >> 9;
        int l = (idx >> 3) & 63;
        int j = idx & 7;
        int k0 = f >> 2, nt = f & 3;
        int row = k0 * 32 + ((l >> 4) << 3) + j;
        int col = (nt << 4) + (l & 15);
        bfrag[idx] = (_Float16)W1[row * 64 + col];
    }
    __syncthreads();

    int lane = tid & 63, wid = tid >> 6;
    float* csw = &cs[wid][0];
    int mrow = lane & 15;          // node row within tile (A and C/D m-index)
    int kgrp = lane >> 4;          // k sub-group
    const half8* bf8 = (const half8*)bfrag;
    int ntiles = (N + 15) >> 4;
    for (int tile = (blockIdx.x << 2) + wid; tile < ntiles; tile += (gridDim.x << 2)) {
        int n0 = tile << 4;
        f32x4 acc0 = {0,0,0,0}, acc1 = {0,0,0,0}, acc2 = {0,0,0,0}, acc3 = {0,0,0,0};
        int arow = n0 + mrow; if (arow >= N) arow = N - 1;
        const float* xr = x + (size_t)arow * IN_C + (kgrp << 3);
        #pragma unroll
        for (int k0 = 0; k0 < 4; ++k0) {
            float4 xa = *(const float4*)(xr + k0 * 32);
            float4 xb = *(const float4*)(xr + k0 * 32 + 4);
            half8 a;
            a[0] = (_Float16)xa.x; a[1] = (_Float16)xa.y;
            a[2] = (_Float16)xa.z; a[3] = (_Float16)xa.w;
            a[4] = (_Float16)xb.x; a[5] = (_Float16)xb.y;
            a[6] = (_Float16)xb.z; a[7] = (_Float16)xb.w;
            acc0 = __builtin_amdgcn_mfma_f32_16x16x32_f16(a, bf8[(k0 * 4 + 0) * 64 + lane], acc0, 0, 0, 0);
            acc1 = __builtin_amdgcn_mfma_f32_16x16x32_f16(a, bf8[(k0 * 4 + 1) * 64 + lane], acc1, 0, 0, 0);
            acc2 = __builtin_amdgcn_mfma_f32_16x16x32_f16(a, bf8[(k0 * 4 + 2) * 64 + lane], acc2, 0, 0, 0);
            acc3 = __builtin_amdgcn_mfma_f32_16x16x32_f16(a, bf8[(k0 * 4 + 3) * 64 + lane], acc3, 0, 0, 0);
        }
        // C/D layout: col = lane&15, row = (lane>>4)*4 + reg   [HW-verified]
        #pragma unroll
        for (int r = 0; r < 4; ++r) {
            int row = (kgrp << 2) + r;
            csw[row * 68 +  0 + mrow] = acc0[r];
            csw[row * 68 + 16 + mrow] = acc1[r];
            csw[row * 68 + 32 + mrow] = acc2[r];
            csw[row * 68 + 48 + mrow] = acc3[r];
        }
        asm volatile("s_waitcnt lgkmcnt(0)" ::: "memory");   // wave-wide LDS RAW fence
        // pass A: write 16 fp16 channels per lane (node = lane>>2, quad = lane&3)
        {
            int node = lane >> 2, cq = lane & 3;
            int n = n0 + node;
            if (n < N) {
                const float* src = &csw[node * 68 + (cq << 4)];
                float4 v0 = *(const float4*)(src);
                float4 v1 = *(const float4*)(src + 4);
                float4 v2 = *(const float4*)(src + 8);
                float4 v3 = *(const float4*)(src + 12);
                unsigned pk[8];
                pk[0] = (unsigned)f2h(v0.x) | ((unsigned)f2h(v0.y) << 16);
                pk[1] = (unsigned)f2h(v0.z) | ((unsigned)f2h(v0.w) << 16);
                pk[2] = (unsigned)f2h(v1.x) | ((unsigned)f2h(v1.y) << 16);
                pk[3] = (unsigned)f2h(v1.z) | ((unsigned)f2h(v1.w) << 16);
                pk[4] = (unsigned)f2h(v2.x) | ((unsigned)f2h(v2.y) << 16);
                pk[5] = (unsigned)f2h(v2.z) | ((unsigned)f2h(v2.w) << 16);
                pk[6] = (unsigned)f2h(v3.x) | ((unsigned)f2h(v3.y) << 16);
                pk[7] = (unsigned)f2h(v3.z) | ((unsigned)f2h(v3.w) << 16);
                char* dst = (char*)(hp + (size_t)n * 48) + (cq << 5);
                ((int4*)dst)[0] = *(int4*)&pk[0];
                ((int4*)dst)[1] = *(int4*)&pk[4];
            }
        }
        // pass B: a_src/a_dst per (node, head), two half-passes
        #pragma unroll
        for (int pr = 0; pr < 2; ++pr) {
            int node = (pr << 3) + (lane >> 3), head = lane & 7;
            int n = n0 + node;
            if (n < N) {
                float s = 0.f, d = 0.f;
                #pragma unroll
                for (int c = 0; c < 8; ++c) {
                    float v = csw[node * 68 + (head << 3) + c];
                    s = fmaf(v, attS[(head << 3) + c], s);
                    d = fmaf(v, attD[(head << 3) + c], d);
                }
                hp[(size_t)n * 48 + 32 + head] = s;
                a_dst1[n * 8 + head] = d;
            }
        }
    }
}

// ---------------- bucket histogram (bin = dst >> 7)
__global__ __launch_bounds__(256) void bucket_count_kernel(
    const int* __restrict__ ei, int* __restrict__ bucketCnt, int E, int Etot, int NB)
{
    __shared__ int hist[NB_MAX];
    int t = threadIdx.x;
    for (int i = t; i < NB; i += 256) hist[i] = 0;
    __syncthreads();
    int base = blockIdx.x * TILE;
    for (int k = t; k < TILE; k += 256) {
        int e = base + k;
        if (e < Etot) {
            int dst = (e < E) ? ei[E + e] : (e - E);   // self-loops appended
            atomicAdd(&hist[dst >> 7], 1);
        }
    }
    __syncthreads();
    for (int i = t; i < NB; i += 256)
        if (hist[i]) atomicAdd(&bucketCnt[i], hist[i]);
}

// ---------------- exclusive scan of bucket counts (1 block; NB <= 1024)
__global__ __launch_bounds__(256) void bucket_scan_kernel(
    const int* __restrict__ cnt, int* __restrict__ base, int* __restrict__ cur,
    int* __restrict__ rowstart, int NB, int N, int Etot)
{
    int t = threadIdx.x;
    int v[4]; int s = 0;
    #pragma unroll
    for (int k = 0; k < 4; ++k) { int i = t * 4 + k; v[k] = (i < NB) ? cnt[i] : 0; s += v[k]; }
    int tsum = s;
    int lane = t & 63, wid = t >> 6;
    for (int off = 1; off < 64; off <<= 1) {
        int u = __shfl_up(s, off);
        if (lane >= off) s += u;
    }
    __shared__ int wsH[4];
    if (lane == 63) wsH[wid] = s;
    __syncthreads();
    int woff = 0;
    for (int w = 0; w < wid; ++w) woff += wsH[w];
    int excl = woff + (s - tsum);
    #pragma unroll
    for (int k = 0; k < 4; ++k) {
        int i = t * 4 + k;
        if (i < NB) {
            base[i] = excl; cur[i] = excl;
            if (i == NB - 1) base[NB] = excl + v[k];
            excl += v[k];
        }
    }
    if (t == 0) rowstart[N] = Etot;
}

// ---------------- partition: bin edges by dst bucket, burst writes per (block,bin)
// packs each edge as (dstLocal<<25)|src  (src < 2^25, dstLocal < 128)
__global__ __launch_bounds__(256) void partition_kernel(
    const int* __restrict__ ei, int* __restrict__ bucketCur,
    unsigned* __restrict__ ebuf, int E, int Etot, int NB)
{
    __shared__ int lcnt[NB_MAX];
    __shared__ int lbase[NB_MAX];
    int t = threadIdx.x;
    for (int i = t; i < NB; i += 256) lcnt[i] = 0;
    __syncthreads();
    int base = blockIdx.x * TILE;
    for (int k = t; k < TILE; k += 256) {
        int e = base + k;
        if (e < Etot) {
            int dst = (e < E) ? ei[E + e] : (e - E);
            atomicAdd(&lcnt[dst >> 7], 1);
        }
    }
    __syncthreads();
    for (int i = t; i < NB; i += 256) {
        int c = lcnt[i];
        lbase[i] = c ? atomicAdd(&bucketCur[i], c) : 0;
    }
    __syncthreads();
    for (int i = t; i < NB; i += 256) lcnt[i] = 0;   // reuse as local rank cursor
    __syncthreads();
    for (int k = t; k < TILE; k += 256) {
        int e = base + k;
        if (e < Etot) {
            int src, dst;
            if (e < E) { src = ei[e]; dst = ei[E + e]; }
            else       { src = dst = e - E; }
            int b = dst >> 7;
            int r = atomicAdd(&lcnt[b], 1);
            ebuf[lbase[b] + r] = ((unsigned)(dst & (B_N - 1)) << 25) | (unsigned)src;
        }
    }
}

// ---------------- per-bucket counting sort -> esrc sorted by node + rowstart
__global__ __launch_bounds__(256) void bucket_sort_kernel(
    const unsigned* __restrict__ ebuf, const int* __restrict__ bucketBase,
    int* __restrict__ rowstart, int* __restrict__ esrc, int N)
{
    __shared__ int lhist[B_N];
    __shared__ int lstart[B_N];
    __shared__ int wsum1;
    int blk = blockIdx.x, t = threadIdx.x;
    int e0 = bucketBase[blk], e1 = bucketBase[blk + 1];
    if (t < B_N) lhist[t] = 0;
    __syncthreads();
    for (int k = e0 + t; k < e1; k += 256)
        atomicAdd(&lhist[ebuf[k] >> 25], 1);
    __syncthreads();
    int lane = t & 63;
    if (t < B_N) {                       // inclusive scan over 2 waves
        int s = lhist[t];
        for (int off = 1; off < 64; off <<= 1) {
            int u = __shfl_up(s, off);
            if (lane >= off) s += u;
        }
        lstart[t] = s;
        if (t == 63) wsum1 = s;          // total of wave 0
    }
    __syncthreads();
    if (t < B_N) {
        int s = lstart[t];
        if (t >= 64) s += wsum1;
        int excl = s - lhist[t];
        lstart[t] = excl;
        int n = blk * B_N + t;
        if (n < N) rowstart[n] = e0 + excl;
    }
    __syncthreads();
    if (t < B_N) lhist[t] = 0;           // reuse as rank cursor
    __syncthreads();
    for (int k = e0 + t; k < e1; k += 256) {
        unsigned pk = ebuf[k];
        int d = pk >> 25;
        int r = atomicAdd(&lhist[d], 1);
        esrc[e0 + lstart[d] + r] = (int)(pk & 0x1FFFFFF);
    }
}

// ---------------- Layer 1 aggregation: wave per dst; lane = eo*32+c2 handles
// channels {2c2,2c2+1} of edge-parity eo. 2 edges/iter + 2-deep unroll.
__global__ __launch_bounds__(256) void agg1_kernel(
    const int* __restrict__ esrc, const int* __restrict__ rowstart,
    const float* __restrict__ hp, const float* __restrict__ a_dst1,
    const float* __restrict__ b1, __half* __restrict__ h2, int N)
{
    int wglobal = (blockIdx.x * 256 + threadIdx.x) >> 6;
    int nwaves = (gridDim.x * 256) >> 6;
    int lane = threadIdx.x & 63;
    int c2 = lane & 31, eo = lane >> 5;
    int h = c2 >> 2;                      // head of channels 2c2,2c2+1
    for (int n = wglobal; n < N; n += nwaves) {
        int end = rowstart[n + 1];
        float ad = a_dst1[n * 8 + h];
        float ax = 0.f, ay = 0.f, wsum = 0.f;
        int p = rowstart[n] + eo;
        for (; p + 2 < end; p += 4) {
            int s0 = esrc[p], s1 = esrc[p + 2];
            const float* r0 = hp + (size_t)s0 * 48;
            const float* r1 = hp + (size_t)s1 * 48;
            float a0 = r0[32 + h] + ad;
            float a1 = r1[32 + h] + ad;
            __half2 q0 = ((const __half2*)r0)[c2];
            __half2 q1 = ((const __half2*)r1)[c2];
            a0 = (a0 > 0.f) ? a0 : NEG * a0;
            a1 = (a1 > 0.f) ? a1 : NEG * a1;
            float w0 = __expf(a0), w1 = __expf(a1);
            ax = fmaf(w0, __low2float(q0), ax);
            ay = fmaf(w0, __high2float(q0), ay);
            ax = fmaf(w1, __low2float(q1), ax);
            ay = fmaf(w1, __high2float(q1), ay);
            wsum += w0 + w1;
        }
        if (p < end) {
            int s0 = esrc[p];
            const float* r0 = hp + (size_t)s0 * 48;
            float a0 = r0[32 + h] + ad;
            __half2 q0 = ((const __half2*)r0)[c2];
            a0 = (a0 > 0.f) ? a0 : NEG * a0;
            float w0 = __expf(a0);
            ax = fmaf(w0, __low2float(q0), ax);
            ay = fmaf(w0, __high2float(q0), ay);
            wsum += w0;
        }
        ax += __shfl_xor(ax, 32);
        ay += __shfl_xor(ay, 32);
        wsum += __shfl_xor(wsum, 32);
        if (eo == 0) {
            float inv = 1.f / (wsum + GAT_EPS);
            float2 bb = *(const float2*)(b1 + 2 * c2);
            float vx = fmaf(ax, inv, bb.x);
            float vy = fmaf(ay, inv, bb.y);
            vx = vx > 0.f ? vx : 0.f;
            vy = vy > 0.f ? vy : 0.f;
            ((__half2*)(h2 + (size_t)n * 64))[c2] =
                __halves2half2(__float2half(vx), __float2half(vy));
        }
    }
}

// ---------------- Layer 2 GEMM: h2(fp16)[N,64] @ W2[64,16] -> packed h2w rows
// h2w row (64 B, float stride 16): [0:32)B = 16 fp16, [32:36)B = fp32 a_src2, pad.
__global__ __launch_bounds__(256) void gemm2_kernel(
    const __half* __restrict__ h2, const float* __restrict__ W2,
    const float* __restrict__ att_s2, const float* __restrict__ att_d2,
    float* __restrict__ h2w, float* __restrict__ a_dst2, int N)
{
    __shared__ float w2s[64 * 16];
    __shared__ float hs[16][64];
    int tid = threadIdx.x;
    for (int i = tid; i < 64 * 16; i += 256) w2s[i] = W2[i];
    int lane = tid & 63, wid = tid >> 6;
    int j = lane & 15, jn = lane >> 4;
    float att_s = att_s2[j], att_d = att_d2[j];
    int ngroups = (N + 15) >> 4;
    for (int grp = blockIdx.x; grp < ngroups; grp += gridDim.x) {
        int nbase = grp * 16;
        __syncthreads();
        for (int i = tid; i < 16 * 32; i += 256) {     // 512 half2 loads
            int rr = i >> 5, cc = i & 31;
            int nn = nbase + rr;
            float lo = 0.f, hi = 0.f;
            if (nn < N) {
                __half2 q = ((const __half2*)(h2 + (size_t)nn * 64))[cc];
                lo = __low2float(q); hi = __high2float(q);
            }
            hs[rr][cc * 2] = lo; hs[rr][cc * 2 + 1] = hi;
        }
        __syncthreads();
        int local = wid * 4 + jn;
        int n = nbase + local;
        float acc = 0.f;
        #pragma unroll 8
        for (int c = 0; c < 64; ++c)
            acc = fmaf(hs[local][c], w2s[c * 16 + j], acc);
        if (n < N) {
            float* row = h2w + (size_t)n * 16;
            ((__half*)row)[j] = __float2half(acc);
            float rs = acc * att_s, rd = acc * att_d;
            rs += __shfl_xor(rs, 1); rd += __shfl_xor(rd, 1);
            rs += __shfl_xor(rs, 2); rd += __shfl_xor(rd, 2);
            rs += __shfl_xor(rs, 4); rd += __shfl_xor(rd, 4);
            rs += __shfl_xor(rs, 8); rd += __shfl_xor(rd, 8);
            if (j == 0) { row[8] = rs; a_dst2[n] = rd; }
        }
    }
}

// ---------------- Layer 2 aggregation: wave per dst; lane = eo*8+c2, 8 edges/iter
__global__ __launch_bounds__(256) void agg2_kernel(
    const int* __restrict__ esrc, const int* __restrict__ rowstart,
    const float* __restrict__ h2w, const float* __restrict__ a_dst2,
    const float* __restrict__ b2, float* __restrict__ out, int N)
{
    int wglobal = (blockIdx.x * 256 + threadIdx.x) >> 6;
    int nwaves = (gridDim.x * 256) >> 6;
    int lane = threadIdx.x & 63;
    int c2 = lane & 7, eo = lane >> 3;
    for (int n = wglobal; n < N; n += nwaves) {
        int start = rowstart[n], end = rowstart[n + 1];
        float ad = a_dst2[n];
        float ax = 0.f, ay = 0.f, wsum = 0.f;
        for (int p = start + eo; p < end; p += 8) {
            int s = esrc[p];
            const float* r = h2w + (size_t)s * 16;
            float a = r[8] + ad;
            __half2 q = ((const __half2*)r)[c2];
            a = (a > 0.f) ? a : NEG * a;
            float w = __expf(a);
            ax = fmaf(w, __low2float(q), ax);
            ay = fmaf(w, __high2float(q), ay);
            wsum += w;
        }
        ax += __shfl_xor(ax, 8);  ay += __shfl_xor(ay, 8);  wsum += __shfl_xor(wsum, 8);
        ax += __shfl_xor(ax, 16); ay += __shfl_xor(ay, 16); wsum += __shfl_xor(wsum, 16);
        ax += __shfl_xor(ax, 32); ay += __shfl_xor(ay, 32); wsum += __shfl_xor(wsum, 32);
        if (eo == 0) {
            float inv = 1.f / (wsum + GAT_EPS);
            float2 bb = *(const float2*)(b2 + 2 * c2);
            float2 o;
            o.x = fmaf(ax, inv, bb.x);
            o.y = fmaf(ay, inv, bb.y);
            o.x = o.x > 0.f ? o.x : 0.f;
            o.y = o.y > 0.f ? o.y : 0.f;
            ((float2*)(out + (size_t)n * 16))[c2] = o;
        }
    }
}

extern "C" void kernel_launch(void* const* d_in, const int* in_sizes, int n_in,
                              void* d_out, int out_size, void* d_ws, size_t ws_size,
                              hipStream_t stream)
{
    const float* x      = (const float*)d_in[0];
    const int*   ei     = (const int*)  d_in[1];   // [2,E] int32
    const float* W1     = (const float*)d_in[2];
    const float* att_s1 = (const float*)d_in[3];
    const float* att_d1 = (const float*)d_in[4];
    const float* b1     = (const float*)d_in[5];
    const float* W2     = (const float*)d_in[6];
    const float* att_s2 = (const float*)d_in[7];
    const float* att_d2 = (const float*)d_in[8];
    const float* b2     = (const float*)d_in[9];
    float* out = (float*)d_out;

    int N = in_sizes[0] / IN_C;
    int E = in_sizes[1] / 2;
    int Etot = E + N;
    int NB = (N + B_N - 1) / B_N;      // 782 for N=100000 (<= NB_MAX)

    // workspace: floats, then ints. ebuf (transient, pre-gemm1) aliases hp.
    float* ws = (float*)d_ws;
    float*  hp     = ws;                               // N*48 (fp16 h + fp32 a_src1)
    __half* h2     = (__half*)(hp + (size_t)N * 48);   // N*64 halves = N*32 floats
    float*  a_dst1 = ((float*)h2) + (size_t)N * 32;    // N*8
    float*  h2w    = a_dst1 + (size_t)N * 8;           // N*16 (fp16 h2w + a_src2)
    float*  a_dst2 = h2w    + (size_t)N * 16;          // N
    int* rowstart   = (int*)(a_dst2 + (size_t)N);      // N+1
    int* bucketCnt  = rowstart   + (N + 1);            // NB_MAX
    int* bucketBase = bucketCnt  + NB_MAX;             // NB_MAX+1
    int* bucketCur  = bucketBase + NB_MAX + 1;         // NB_MAX
    int* esrc       = bucketCur  + NB_MAX;             // Etot
    unsigned* ebuf  = (unsigned*)hp;                   // Etot ints (transient alias)

    int egrid = (Etot + TILE - 1) / TILE;

    // ---- CSR build: bucket partition + per-bucket counting sort ----
    hipMemsetAsync(bucketCnt, 0, NB_MAX * sizeof(int), stream);
    bucket_count_kernel<<<egrid, 256, 0, stream>>>(ei, bucketCnt, E, Etot, NB);
    bucket_scan_kernel<<<1, 256, 0, stream>>>(bucketCnt, bucketBase, bucketCur,
                                              rowstart, NB, N, Etot);
    partition_kernel<<<egrid, 256, 0, stream>>>(ei, bucketCur, ebuf, E, Etot, NB);
    bucket_sort_kernel<<<NB, 256, 0, stream>>>(ebuf, bucketBase, rowstart, esrc, N);

    // ---- layer 1 ----
    gemm1_kernel<<<512, 256, 0, stream>>>(x, W1, att_s1, att_d1, hp, a_dst1, N);
    agg1_kernel<<<2048, 256, 0, stream>>>(esrc, rowstart, hp, a_dst1, b1, h2, N);

    // ---- layer 2 ----
    gemm2_kernel<<<1024, 256, 0, stream>>>(h2, W2, att_s2, att_d2, h2w, a_dst2, N);
    agg2_kernel<<<1024, 256, 0, stream>>>(esrc, rowstart, h2w, a_dst2, b2, out, N);
}

// Round 10
// 211.363 us; speedup vs baseline: 5.6815x; 1.1329x over previous
//
#include <hip/hip_runtime.h>
#include <hip/hip_fp16.h>

#define IN_C 128
#define NEG 0.2f
#define GAT_EPS 1e-16f
#define B_N 128            // dst nodes per bucket (dstLocal fits in 7 bits)
#define NB_MAX 1024        // supports N <= 131072
#define TILE 8192          // edges per partition block

typedef _Float16 half8 __attribute__((ext_vector_type(8)));
typedef float f32x4 __attribute__((ext_vector_type(4)));

static __device__ inline unsigned f2h(float f) {
    _Float16 h = (_Float16)f;
    unsigned short u;
    __builtin_memcpy(&u, &h, 2);
    return (unsigned)u;
}

// ---------------- Layer 1 GEMM (MFMA): x[N,128] @ W1[128,64] -> hp fp16[N,64] (128 B rows)
// + a_src1[N,8], a_dst1[N,8] fp32. One wave per 16-node tile: 4 K-chunks x 4 N-tiles.
__global__ __launch_bounds__(256) void gemm1_kernel(
    const float* __restrict__ x, const float* __restrict__ W1,
    const float* __restrict__ att_s1, const float* __restrict__ att_d1,
    float* __restrict__ hp, float* __restrict__ a_src1, float* __restrict__ a_dst1, int N)
{
    __shared__ _Float16 bfrag[16 * 512];   // 16 KB: frag f, lane l, elem j at f*512+l*8+j
    __shared__ float cs[4][16 * 68];       // per-wave C staging, padded stride 68
    __shared__ float attS[64], attD[64];
    int tid = threadIdx.x;
    if (tid < 64) { attS[tid] = att_s1[tid]; attD[tid] = att_d1[tid]; }
    // B frags: f=(k0*4+nt); lane holds W1[k0*32+(l>>4)*8+j][nt*16+(l&15)]
    // (k-map only needs to match the A-pack's k-map — any consistent bijection works.)
    for (int idx = tid; idx < 8192; idx += 256) {
        int f = idx >> 9;
        int l = (idx >> 3) & 63;
        int j = idx & 7;
        int k0 = f >> 2, nt = f & 3;
        int row = k0 * 32 + ((l >> 4) << 3) + j;
        int col = (nt << 4) + (l & 15);
        bfrag[idx] = (_Float16)W1[row * 64 + col];
    }
    __syncthreads();

    int lane = tid & 63, wid = tid >> 6;
    float* csw = &cs[wid][0];
    int mrow = lane & 15;          // node row within tile
    int kgrp = lane >> 4;          // k sub-group
    const half8* bf8 = (const half8*)bfrag;
    int ntiles = (N + 15) >> 4;
    for (int tile = (blockIdx.x << 2) + wid; tile < ntiles; tile += (gridDim.x << 2)) {
        int n0 = tile << 4;
        f32x4 acc0 = {0,0,0,0}, acc1 = {0,0,0,0}, acc2 = {0,0,0,0}, acc3 = {0,0,0,0};
        int arow = n0 + mrow; if (arow >= N) arow = N - 1;
        const float* xr = x + (size_t)arow * IN_C + (kgrp << 3);
        #pragma unroll
        for (int k0 = 0; k0 < 4; ++k0) {
            float4 xa = *(const float4*)(xr + k0 * 32);
            float4 xb = *(const float4*)(xr + k0 * 32 + 4);
            half8 a;
            a[0] = (_Float16)xa.x; a[1] = (_Float16)xa.y;
            a[2] = (_Float16)xa.z; a[3] = (_Float16)xa.w;
            a[4] = (_Float16)xb.x; a[5] = (_Float16)xb.y;
            a[6] = (_Float16)xb.z; a[7] = (_Float16)xb.w;
            acc0 = __builtin_amdgcn_mfma_f32_16x16x32_f16(a, bf8[(k0 * 4 + 0) * 64 + lane], acc0, 0, 0, 0);
            acc1 = __builtin_amdgcn_mfma_f32_16x16x32_f16(a, bf8[(k0 * 4 + 1) * 64 + lane], acc1, 0, 0, 0);
            acc2 = __builtin_amdgcn_mfma_f32_16x16x32_f16(a, bf8[(k0 * 4 + 2) * 64 + lane], acc2, 0, 0, 0);
            acc3 = __builtin_amdgcn_mfma_f32_16x16x32_f16(a, bf8[(k0 * 4 + 3) * 64 + lane], acc3, 0, 0, 0);
        }
        // C/D layout: col = lane&15, row = (lane>>4)*4 + reg   [HW-verified]
        #pragma unroll
        for (int r = 0; r < 4; ++r) {
            int row = (kgrp << 2) + r;
            csw[row * 68 +  0 + mrow] = acc0[r];
            csw[row * 68 + 16 + mrow] = acc1[r];
            csw[row * 68 + 32 + mrow] = acc2[r];
            csw[row * 68 + 48 + mrow] = acc3[r];
        }
        asm volatile("s_waitcnt lgkmcnt(0)" ::: "memory");   // wave-wide LDS RAW fence
        // pass A: 16 fp16 channels per lane (node = lane>>2, quad = lane&3)
        {
            int node = lane >> 2, cq = lane & 3;
            int n = n0 + node;
            if (n < N) {
                const float* src = &csw[node * 68 + (cq << 4)];
                float4 v0 = *(const float4*)(src);
                float4 v1 = *(const float4*)(src + 4);
                float4 v2 = *(const float4*)(src + 8);
                float4 v3 = *(const float4*)(src + 12);
                unsigned pk[8];
                pk[0] = f2h(v0.x) | (f2h(v0.y) << 16);
                pk[1] = f2h(v0.z) | (f2h(v0.w) << 16);
                pk[2] = f2h(v1.x) | (f2h(v1.y) << 16);
                pk[3] = f2h(v1.z) | (f2h(v1.w) << 16);
                pk[4] = f2h(v2.x) | (f2h(v2.y) << 16);
                pk[5] = f2h(v2.z) | (f2h(v2.w) << 16);
                pk[6] = f2h(v3.x) | (f2h(v3.y) << 16);
                pk[7] = f2h(v3.z) | (f2h(v3.w) << 16);
                char* dst = (char*)(hp + (size_t)n * 32) + (cq << 5);
                ((int4*)dst)[0] = *(int4*)&pk[0];
                ((int4*)dst)[1] = *(int4*)&pk[4];
            }
        }
        // pass B: a_src/a_dst per (node, head), two half-passes
        #pragma unroll
        for (int pr = 0; pr < 2; ++pr) {
            int node = (pr << 3) + (lane >> 3), head = lane & 7;
            int n = n0 + node;
            if (n < N) {
                float s = 0.f, d = 0.f;
                #pragma unroll
                for (int c = 0; c < 8; ++c) {
                    float v = csw[node * 68 + (head << 3) + c];
                    s = fmaf(v, attS[(head << 3) + c], s);
                    d = fmaf(v, attD[(head << 3) + c], d);
                }
                a_src1[n * 8 + head] = s;
                a_dst1[n * 8 + head] = d;
            }
        }
    }
}

// ---------------- bucket histogram (bin = dst >> 7)
__global__ __launch_bounds__(256) void bucket_count_kernel(
    const int* __restrict__ ei, int* __restrict__ bucketCnt, int E, int Etot, int NB)
{
    __shared__ int hist[NB_MAX];
    int t = threadIdx.x;
    for (int i = t; i < NB; i += 256) hist[i] = 0;
    __syncthreads();
    int base = blockIdx.x * TILE;
    for (int k = t; k < TILE; k += 256) {
        int e = base + k;
        if (e < Etot) {
            int dst = (e < E) ? ei[E + e] : (e - E);   // self-loops appended
            atomicAdd(&hist[dst >> 7], 1);
        }
    }
    __syncthreads();
    for (int i = t; i < NB; i += 256)
        if (hist[i]) atomicAdd(&bucketCnt[i], hist[i]);
}

// ---------------- exclusive scan of bucket counts (1 block; NB <= 1024)
__global__ __launch_bounds__(256) void bucket_scan_kernel(
    const int* __restrict__ cnt, int* __restrict__ base, int* __restrict__ cur,
    int* __restrict__ rowstart, int NB, int N, int Etot)
{
    int t = threadIdx.x;
    int v[4]; int s = 0;
    #pragma unroll
    for (int k = 0; k < 4; ++k) { int i = t * 4 + k; v[k] = (i < NB) ? cnt[i] : 0; s += v[k]; }
    int tsum = s;
    int lane = t & 63, wid = t >> 6;
    for (int off = 1; off < 64; off <<= 1) {
        int u = __shfl_up(s, off);
        if (lane >= off) s += u;
    }
    __shared__ int wsH[4];
    if (lane == 63) wsH[wid] = s;
    __syncthreads();
    int woff = 0;
    for (int w = 0; w < wid; ++w) woff += wsH[w];
    int excl = woff + (s - tsum);
    #pragma unroll
    for (int k = 0; k < 4; ++k) {
        int i = t * 4 + k;
        if (i < NB) {
            base[i] = excl; cur[i] = excl;
            if (i == NB - 1) base[NB] = excl + v[k];
            excl += v[k];
        }
    }
    if (t == 0) rowstart[N] = Etot;
}

// ---------------- partition: bin edges by dst bucket, burst writes per (block,bin)
// packs each edge as (dstLocal<<25)|src  (src < 2^25, dstLocal < 128)
__global__ __launch_bounds__(256) void partition_kernel(
    const int* __restrict__ ei, int* __restrict__ bucketCur,
    unsigned* __restrict__ ebuf, int E, int Etot, int NB)
{
    __shared__ int lcnt[NB_MAX];
    __shared__ int lbase[NB_MAX];
    int t = threadIdx.x;
    for (int i = t; i < NB; i += 256) lcnt[i] = 0;
    __syncthreads();
    int base = blockIdx.x * TILE;
    for (int k = t; k < TILE; k += 256) {
        int e = base + k;
        if (e < Etot) {
            int dst = (e < E) ? ei[E + e] : (e - E);
            atomicAdd(&lcnt[dst >> 7], 1);
        }
    }
    __syncthreads();
    for (int i = t; i < NB; i += 256) {
        int c = lcnt[i];
        lbase[i] = c ? atomicAdd(&bucketCur[i], c) : 0;
    }
    __syncthreads();
    for (int i = t; i < NB; i += 256) lcnt[i] = 0;   // reuse as local rank cursor
    __syncthreads();
    for (int k = t; k < TILE; k += 256) {
        int e = base + k;
        if (e < Etot) {
            int src, dst;
            if (e < E) { src = ei[e]; dst = ei[E + e]; }
            else       { src = dst = e - E; }
            int b = dst >> 7;
            int r = atomicAdd(&lcnt[b], 1);
            ebuf[lbase[b] + r] = ((unsigned)(dst & (B_N - 1)) << 25) | (unsigned)src;
        }
    }
}

// ---------------- per-bucket counting sort -> esrc sorted by node + rowstart
__global__ __launch_bounds__(256) void bucket_sort_kernel(
    const unsigned* __restrict__ ebuf, const int* __restrict__ bucketBase,
    int* __restrict__ rowstart, int* __restrict__ esrc, int N)
{
    __shared__ int lhist[B_N];
    __shared__ int lstart[B_N];
    __shared__ int wsum1;
    int blk = blockIdx.x, t = threadIdx.x;
    int e0 = bucketBase[blk], e1 = bucketBase[blk + 1];
    if (t < B_N) lhist[t] = 0;
    __syncthreads();
    for (int k = e0 + t; k < e1; k += 256)
        atomicAdd(&lhist[ebuf[k] >> 25], 1);
    __syncthreads();
    int lane = t & 63;
    if (t < B_N) {                       // inclusive scan over 2 waves
        int s = lhist[t];
        for (int off = 1; off < 64; off <<= 1) {
            int u = __shfl_up(s, off);
            if (lane >= off) s += u;
        }
        lstart[t] = s;
        if (t == 63) wsum1 = s;          // total of wave 0
    }
    __syncthreads();
    if (t < B_N) {
        int s = lstart[t];
        if (t >= 64) s += wsum1;
        int excl = s - lhist[t];
        lstart[t] = excl;
        int n = blk * B_N + t;
        if (n < N) rowstart[n] = e0 + excl;
    }
    __syncthreads();
    if (t < B_N) lhist[t] = 0;           // reuse as rank cursor
    __syncthreads();
    for (int k = e0 + t; k < e1; k += 256) {
        unsigned pk = ebuf[k];
        int d = pk >> 25;
        int r = atomicAdd(&lhist[d], 1);
        esrc[e0 + lstart[d] + r] = (int)(pk & 0x1FFFFFF);
    }
}

// ---------------- Layer 1 aggregation: wave per dst; lane = eo*32+c2 handles
// channels {2c2,2c2+1} of edge-parity eo. 4 edges in flight.
__global__ __launch_bounds__(256) void agg1_kernel(
    const int* __restrict__ esrc, const int* __restrict__ rowstart,
    const float* __restrict__ hp, const float* __restrict__ a_src1,
    const float* __restrict__ a_dst1, const float* __restrict__ b1,
    __half* __restrict__ h2, int N)
{
    int wglobal = (blockIdx.x * 256 + threadIdx.x) >> 6;
    int nwaves = (gridDim.x * 256) >> 6;
    int lane = threadIdx.x & 63;
    int c2 = lane & 31, eo = lane >> 5;
    int h = c2 >> 2;                      // head of channels 2c2,2c2+1
    for (int n = wglobal; n < N; n += nwaves) {
        int end = rowstart[n + 1];
        float ad = a_dst1[n * 8 + h];
        float ax = 0.f, ay = 0.f, wsum = 0.f;
        int p = rowstart[n] + eo;
        for (; p + 6 < end; p += 8) {        // 4 edges in flight per lane
            int s0 = esrc[p], s1 = esrc[p + 2], s2 = esrc[p + 4], s3 = esrc[p + 6];
            float a0 = a_src1[s0 * 8 + h] + ad;
            float a1 = a_src1[s1 * 8 + h] + ad;
            float a2 = a_src1[s2 * 8 + h] + ad;
            float a3 = a_src1[s3 * 8 + h] + ad;
            __half2 q0 = ((const __half2*)(hp + (size_t)s0 * 32))[c2];
            __half2 q1 = ((const __half2*)(hp + (size_t)s1 * 32))[c2];
            __half2 q2 = ((const __half2*)(hp + (size_t)s2 * 32))[c2];
            __half2 q3 = ((const __half2*)(hp + (size_t)s3 * 32))[c2];
            a0 = (a0 > 0.f) ? a0 : NEG * a0;
            a1 = (a1 > 0.f) ? a1 : NEG * a1;
            a2 = (a2 > 0.f) ? a2 : NEG * a2;
            a3 = (a3 > 0.f) ? a3 : NEG * a3;
            float w0 = __expf(a0), w1 = __expf(a1), w2 = __expf(a2), w3 = __expf(a3);
            ax = fmaf(w0, __low2float(q0), ax);  ay = fmaf(w0, __high2float(q0), ay);
            ax = fmaf(w1, __low2float(q1), ax);  ay = fmaf(w1, __high2float(q1), ay);
            ax = fmaf(w2, __low2float(q2), ax);  ay = fmaf(w2, __high2float(q2), ay);
            ax = fmaf(w3, __low2float(q3), ax);  ay = fmaf(w3, __high2float(q3), ay);
            wsum += (w0 + w1) + (w2 + w3);
        }
        for (; p < end; p += 2) {
            int s0 = esrc[p];
            float a0 = a_src1[s0 * 8 + h] + ad;
            __half2 q0 = ((const __half2*)(hp + (size_t)s0 * 32))[c2];
            a0 = (a0 > 0.f) ? a0 : NEG * a0;
            float w0 = __expf(a0);
            ax = fmaf(w0, __low2float(q0), ax);
            ay = fmaf(w0, __high2float(q0), ay);
            wsum += w0;
        }
        ax += __shfl_xor(ax, 32);
        ay += __shfl_xor(ay, 32);
        wsum += __shfl_xor(wsum, 32);
        if (eo == 0) {
            float inv = 1.f / (wsum + GAT_EPS);
            float2 bb = *(const float2*)(b1 + 2 * c2);
            float vx = fmaf(ax, inv, bb.x);
            float vy = fmaf(ay, inv, bb.y);
            vx = vx > 0.f ? vx : 0.f;
            vy = vy > 0.f ? vy : 0.f;
            ((__half2*)(h2 + (size_t)n * 64))[c2] =
                __halves2half2(__float2half(vx), __float2half(vy));
        }
    }
}

// ---------------- Layer 2 GEMM (MFMA): h2(fp16)[N,64] @ W2[64,16] -> h2w fp16[N,16]
// + a_src2[N], a_dst2[N]. One wave per 16-node tile: 2 MFMAs (K=64).
__global__ __launch_bounds__(256) void gemm2_kernel(
    const __half* __restrict__ h2, const float* __restrict__ W2,
    const float* __restrict__ att_s2, const float* __restrict__ att_d2,
    __half* __restrict__ h2w, float* __restrict__ a_src2, float* __restrict__ a_dst2, int N)
{
    __shared__ _Float16 bfrag[2 * 512];   // 2 KB: frag k0, lane l, elem j
    __shared__ float cs[4][16 * 20];      // per-wave C staging, padded stride 20
    int tid = threadIdx.x;
    for (int idx = tid; idx < 1024; idx += 256) {
        int f = idx >> 9, l = (idx >> 3) & 63, j = idx & 7;
        int row = f * 32 + ((l >> 4) << 3) + j;   // same k-map as A-pack
        int col = l & 15;
        bfrag[idx] = (_Float16)W2[row * 16 + col];
    }
    __syncthreads();
    int lane = tid & 63, wid = tid >> 6;
    int mrow = lane & 15, kgrp = lane >> 4;
    float* csw = &cs[wid][0];
    const half8* bf8 = (const half8*)bfrag;
    int ech = (lane & 3) << 2;            // epilogue channel block
    float as0 = att_s2[ech], as1 = att_s2[ech + 1], as2 = att_s2[ech + 2], as3 = att_s2[ech + 3];
    float ad0 = att_d2[ech], ad1 = att_d2[ech + 1], ad2 = att_d2[ech + 2], ad3 = att_d2[ech + 3];
    int ntiles = (N + 15) >> 4;
    for (int tile = (blockIdx.x << 2) + wid; tile < ntiles; tile += (gridDim.x << 2)) {
        int n0 = tile << 4;
        f32x4 acc = {0, 0, 0, 0};
        int arow = n0 + mrow; if (arow >= N) arow = N - 1;
        const half8* h2r = (const half8*)(h2 + (size_t)arow * 64 + (kgrp << 3));
        acc = __builtin_amdgcn_mfma_f32_16x16x32_f16(h2r[0], bf8[lane], acc, 0, 0, 0);
        acc = __builtin_amdgcn_mfma_f32_16x16x32_f16(h2r[4], bf8[64 + lane], acc, 0, 0, 0);
        #pragma unroll
        for (int r = 0; r < 4; ++r)
            csw[((kgrp << 2) + r) * 20 + mrow] = acc[r];
        asm volatile("s_waitcnt lgkmcnt(0)" ::: "memory");
        int node = lane >> 2;
        int n = n0 + node;
        if (n < N) {
            float4 v = *(const float4*)&csw[node * 20 + ech];
            unsigned pk0 = f2h(v.x) | (f2h(v.y) << 16);
            unsigned pk1 = f2h(v.z) | (f2h(v.w) << 16);
            *(int2*)((char*)(h2w + (size_t)n * 16) + (ech << 1)) = make_int2((int)pk0, (int)pk1);
            float s = fmaf(v.x, as0, fmaf(v.y, as1, fmaf(v.z, as2, v.w * as3)));
            float d = fmaf(v.x, ad0, fmaf(v.y, ad1, fmaf(v.z, ad2, v.w * ad3)));
            s += __shfl_xor(s, 1); d += __shfl_xor(d, 1);
            s += __shfl_xor(s, 2); d += __shfl_xor(d, 2);
            if ((lane & 3) == 0) { a_src2[n] = s; a_dst2[n] = d; }
        }
    }
}

// ---------------- Layer 2 aggregation: wave per dst; lane = eo*8+c2, 8 edges/iter
__global__ __launch_bounds__(256) void agg2_kernel(
    const int* __restrict__ esrc, const int* __restrict__ rowstart,
    const __half* __restrict__ h2w, const float* __restrict__ a_src2,
    const float* __restrict__ a_dst2, const float* __restrict__ b2,
    float* __restrict__ out, int N)
{
    int wglobal = (blockIdx.x * 256 + threadIdx.x) >> 6;
    int nwaves = (gridDim.x * 256) >> 6;
    int lane = threadIdx.x & 63;
    int c2 = lane & 7, eo = lane >> 3;
    for (int n = wglobal; n < N; n += nwaves) {
        int start = rowstart[n], end = rowstart[n + 1];
        float ad = a_dst2[n];
        float ax = 0.f, ay = 0.f, wsum = 0.f;
        for (int p = start + eo; p < end; p += 8) {
            int s = esrc[p];
            float a = a_src2[s] + ad;
            __half2 q = ((const __half2*)(h2w + (size_t)s * 16))[c2];
            a = (a > 0.f) ? a : NEG * a;
            float w = __expf(a);
            ax = fmaf(w, __low2float(q), ax);
            ay = fmaf(w, __high2float(q), ay);
            wsum += w;
        }
        ax += __shfl_xor(ax, 8);  ay += __shfl_xor(ay, 8);  wsum += __shfl_xor(wsum, 8);
        ax += __shfl_xor(ax, 16); ay += __shfl_xor(ay, 16); wsum += __shfl_xor(wsum, 16);
        ax += __shfl_xor(ax, 32); ay += __shfl_xor(ay, 32); wsum += __shfl_xor(wsum, 32);
        if (eo == 0) {
            float inv = 1.f / (wsum + GAT_EPS);
            float2 bb = *(const float2*)(b2 + 2 * c2);
            float2 o;
            o.x = fmaf(ax, inv, bb.x);
            o.y = fmaf(ay, inv, bb.y);
            o.x = o.x > 0.f ? o.x : 0.f;
            o.y = o.y > 0.f ? o.y : 0.f;
            ((float2*)(out + (size_t)n * 16))[c2] = o;
        }
    }
}

extern "C" void kernel_launch(void* const* d_in, const int* in_sizes, int n_in,
                              void* d_out, int out_size, void* d_ws, size_t ws_size,
                              hipStream_t stream)
{
    const float* x      = (const float*)d_in[0];
    const int*   ei     = (const int*)  d_in[1];   // [2,E] int32
    const float* W1     = (const float*)d_in[2];
    const float* att_s1 = (const float*)d_in[3];
    const float* att_d1 = (const float*)d_in[4];
    const float* b1     = (const float*)d_in[5];
    const float* W2     = (const float*)d_in[6];
    const float* att_s2 = (const float*)d_in[7];
    const float* att_d2 = (const float*)d_in[8];
    const float* b2     = (const float*)d_in[9];
    float* out = (float*)d_out;

    int N = in_sizes[0] / IN_C;
    int E = in_sizes[1] / 2;
    int Etot = E + N;
    int NB = (N + B_N - 1) / B_N;      // 782 for N=100000 (<= NB_MAX)

    // workspace: floats, then ints. ebuf (transient, pre-gemm1) aliases hp.
    float* ws = (float*)d_ws;
    float*  hp     = ws;                               // N*32 (fp16 h, 128 B rows)
    float*  a_src1 = hp + (size_t)N * 32;              // N*8
    float*  a_dst1 = a_src1 + (size_t)N * 8;           // N*8
    __half* h2     = (__half*)(a_dst1 + (size_t)N * 8);// N*64 halves = N*32 floats
    __half* h2w    = (__half*)((float*)h2 + (size_t)N * 32); // N*16 halves = N*8 floats
    float*  a_src2 = (float*)h2w + (size_t)N * 8;      // N
    float*  a_dst2 = a_src2 + (size_t)N;               // N
    int* rowstart   = (int*)(a_dst2 + (size_t)N);      // N+1
    int* bucketCnt  = rowstart   + (N + 1);            // NB_MAX
    int* bucketBase = bucketCnt  + NB_MAX;             // NB_MAX+1
    int* bucketCur  = bucketBase + NB_MAX + 1;         // NB_MAX
    int* esrc       = bucketCur  + NB_MAX;             // Etot
    unsigned* ebuf  = (unsigned*)hp;                   // Etot ints (transient alias)

    int egrid = (Etot + TILE - 1) / TILE;

    // ---- CSR build: bucket partition + per-bucket counting sort ----
    hipMemsetAsync(bucketCnt, 0, NB_MAX * sizeof(int), stream);
    bucket_count_kernel<<<egrid, 256, 0, stream>>>(ei, bucketCnt, E, Etot, NB);
    bucket_scan_kernel<<<1, 256, 0, stream>>>(bucketCnt, bucketBase, bucketCur,
                                              rowstart, NB, N, Etot);
    partition_kernel<<<egrid, 256, 0, stream>>>(ei, bucketCur, ebuf, E, Etot, NB);
    bucket_sort_kernel<<<NB, 256, 0, stream>>>(ebuf, bucketBase, rowstart, esrc, N);

    // ---- layer 1 ----
    gemm1_kernel<<<512, 256, 0, stream>>>(x, W1, att_s1, att_d1, hp, a_src1, a_dst1, N);
    agg1_kernel<<<2048, 256, 0, stream>>>(esrc, rowstart, hp, a_src1, a_dst1, b1, h2, N);

    // ---- layer 2 ----
    gemm2_kernel<<<512, 256, 0, stream>>>(h2, W2, att_s2, att_d2, h2w, a_src2, a_dst2, N);
    agg2_kernel<<<1024, 256, 0, stream>>>(esrc, rowstart, h2w, a_src2, a_dst2, b2, out, N);
}

// Round 11
// 210.083 us; speedup vs baseline: 5.7161x; 1.0061x over previous
//
#include <hip/hip_runtime.h>
#include <hip/hip_fp16.h>

#define IN_C 128
#define NEG 0.2f
#define GAT_EPS 1e-16f
#define B_N 128            // dst nodes per bucket (dstLocal fits in 7 bits)
#define NB_MAX 1024        // supports N <= 131072
#define TILE 8192          // edges per partition block
#define GEMM_BLKS 1024     // gemm1 blocks inside fused K1

typedef _Float16 half8 __attribute__((ext_vector_type(8)));
typedef float f32x4 __attribute__((ext_vector_type(4)));

static __device__ inline unsigned f2h(float f) {
    _Float16 h = (_Float16)f;
    unsigned short u;
    __builtin_memcpy(&u, &h, 2);
    return (unsigned)u;
}

// ---------------- Fused K1: gemm1 (MFMA) on blocks [0,GEMM_BLKS) +
// bucket histogram on blocks [GEMM_BLKS, GEMM_BLKS+egrid).
// gemm1: x[N,128] @ W1[128,64] -> hp fp16[N,64] (128 B rows) + a_src1 fp16[N,8] + a_dst1 fp32[N,8]
__global__ __launch_bounds__(256) void k1_kernel(
    const float* __restrict__ x, const float* __restrict__ W1,
    const float* __restrict__ att_s1, const float* __restrict__ att_d1,
    float* __restrict__ hp, __half* __restrict__ a_src1, float* __restrict__ a_dst1,
    const int* __restrict__ ei, int* __restrict__ bucketCnt,
    int E, int Etot, int NB, int N)
{
    __shared__ __align__(16) char smem[34304];   // 16K bfrag + 17K cs + 512B att
    int tid = threadIdx.x;

    if ((int)blockIdx.x >= GEMM_BLKS) {
        // ---- bucket_count branch ----
        int* hist = (int*)smem;
        for (int i = tid; i < NB; i += 256) hist[i] = 0;
        __syncthreads();
        int base = ((int)blockIdx.x - GEMM_BLKS) * TILE;
        for (int k = tid; k < TILE; k += 256) {
            int e = base + k;
            if (e < Etot) {
                int dst = (e < E) ? ei[E + e] : (e - E);   // self-loops appended
                atomicAdd(&hist[dst >> 7], 1);
            }
        }
        __syncthreads();
        for (int i = tid; i < NB; i += 256)
            if (hist[i]) atomicAdd(&bucketCnt[i], hist[i]);
        return;
    }

    // ---- gemm1 branch ----
    _Float16* bfrag = (_Float16*)smem;                   // 16 KB
    float* csbase   = (float*)(smem + 16384);            // 4 waves x 16x68
    float* attS     = (float*)(smem + 16384 + 17408);
    float* attD     = attS + 64;
    if (tid < 64) { attS[tid] = att_s1[tid]; attD[tid] = att_d1[tid]; }
    // B frags: f=(k0*4+nt); lane holds W1[k0*32+(l>>4)*8+j][nt*16+(l&15)]
    // (k-map only needs to match the A-pack's k-map.)
    for (int idx = tid; idx < 8192; idx += 256) {
        int f = idx >> 9;
        int l = (idx >> 3) & 63;
        int j = idx & 7;
        int k0 = f >> 2, nt = f & 3;
        int row = k0 * 32 + ((l >> 4) << 3) + j;
        int col = (nt << 4) + (l & 15);
        bfrag[idx] = (_Float16)W1[row * 64 + col];
    }
    __syncthreads();

    int lane = tid & 63, wid = tid >> 6;
    float* csw = csbase + wid * (16 * 68);
    int mrow = lane & 15;          // node row within tile
    int kgrp = lane >> 4;          // k sub-group
    const half8* bf8 = (const half8*)bfrag;
    int ntiles = (N + 15) >> 4;
    for (int tile = ((int)blockIdx.x << 2) + wid; tile < ntiles; tile += (GEMM_BLKS << 2)) {
        int n0 = tile << 4;
        f32x4 acc0 = {0,0,0,0}, acc1 = {0,0,0,0}, acc2 = {0,0,0,0}, acc3 = {0,0,0,0};
        int arow = n0 + mrow; if (arow >= N) arow = N - 1;
        const float* xr = x + (size_t)arow * IN_C + (kgrp << 3);
        #pragma unroll
        for (int k0 = 0; k0 < 4; ++k0) {
            float4 xa = *(const float4*)(xr + k0 * 32);
            float4 xb = *(const float4*)(xr + k0 * 32 + 4);
            half8 a;
            a[0] = (_Float16)xa.x; a[1] = (_Float16)xa.y;
            a[2] = (_Float16)xa.z; a[3] = (_Float16)xa.w;
            a[4] = (_Float16)xb.x; a[5] = (_Float16)xb.y;
            a[6] = (_Float16)xb.z; a[7] = (_Float16)xb.w;
            acc0 = __builtin_amdgcn_mfma_f32_16x16x32_f16(a, bf8[(k0 * 4 + 0) * 64 + lane], acc0, 0, 0, 0);
            acc1 = __builtin_amdgcn_mfma_f32_16x16x32_f16(a, bf8[(k0 * 4 + 1) * 64 + lane], acc1, 0, 0, 0);
            acc2 = __builtin_amdgcn_mfma_f32_16x16x32_f16(a, bf8[(k0 * 4 + 2) * 64 + lane], acc2, 0, 0, 0);
            acc3 = __builtin_amdgcn_mfma_f32_16x16x32_f16(a, bf8[(k0 * 4 + 3) * 64 + lane], acc3, 0, 0, 0);
        }
        // C/D layout: col = lane&15, row = (lane>>4)*4 + reg   [HW-verified]
        #pragma unroll
        for (int r = 0; r < 4; ++r) {
            int row = (kgrp << 2) + r;
            csw[row * 68 +  0 + mrow] = acc0[r];
            csw[row * 68 + 16 + mrow] = acc1[r];
            csw[row * 68 + 32 + mrow] = acc2[r];
            csw[row * 68 + 48 + mrow] = acc3[r];
        }
        asm volatile("s_waitcnt lgkmcnt(0)" ::: "memory");   // wave-wide LDS RAW fence
        // pass A: 16 fp16 channels per lane (node = lane>>2, quad = lane&3)
        {
            int node = lane >> 2, cq = lane & 3;
            int n = n0 + node;
            if (n < N) {
                const float* src = &csw[node * 68 + (cq << 4)];
                float4 v0 = *(const float4*)(src);
                float4 v1 = *(const float4*)(src + 4);
                float4 v2 = *(const float4*)(src + 8);
                float4 v3 = *(const float4*)(src + 12);
                unsigned pk[8];
                pk[0] = f2h(v0.x) | (f2h(v0.y) << 16);
                pk[1] = f2h(v0.z) | (f2h(v0.w) << 16);
                pk[2] = f2h(v1.x) | (f2h(v1.y) << 16);
                pk[3] = f2h(v1.z) | (f2h(v1.w) << 16);
                pk[4] = f2h(v2.x) | (f2h(v2.y) << 16);
                pk[5] = f2h(v2.z) | (f2h(v2.w) << 16);
                pk[6] = f2h(v3.x) | (f2h(v3.y) << 16);
                pk[7] = f2h(v3.z) | (f2h(v3.w) << 16);
                char* dst = (char*)(hp + (size_t)n * 32) + (cq << 5);
                ((int4*)dst)[0] = *(int4*)&pk[0];
                ((int4*)dst)[1] = *(int4*)&pk[4];
            }
        }
        // pass B: a_src/a_dst per (node, head), two half-passes
        #pragma unroll
        for (int pr = 0; pr < 2; ++pr) {
            int node = (pr << 3) + (lane >> 3), head = lane & 7;
            int n = n0 + node;
            if (n < N) {
                float s = 0.f, d = 0.f;
                #pragma unroll
                for (int c = 0; c < 8; ++c) {
                    float v = csw[node * 68 + (head << 3) + c];
                    s = fmaf(v, attS[(head << 3) + c], s);
                    d = fmaf(v, attD[(head << 3) + c], d);
                }
                a_src1[n * 8 + head] = __float2half(s);
                a_dst1[n * 8 + head] = d;
            }
        }
    }
}

// ---------------- exclusive scan of bucket counts (1 block; NB <= 1024)
__global__ __launch_bounds__(256) void bucket_scan_kernel(
    const int* __restrict__ cnt, int* __restrict__ base, int* __restrict__ cur,
    int* __restrict__ rowstart, int NB, int N, int Etot)
{
    int t = threadIdx.x;
    int v[4]; int s = 0;
    #pragma unroll
    for (int k = 0; k < 4; ++k) { int i = t * 4 + k; v[k] = (i < NB) ? cnt[i] : 0; s += v[k]; }
    int tsum = s;
    int lane = t & 63, wid = t >> 6;
    for (int off = 1; off < 64; off <<= 1) {
        int u = __shfl_up(s, off);
        if (lane >= off) s += u;
    }
    __shared__ int wsH[4];
    if (lane == 63) wsH[wid] = s;
    __syncthreads();
    int woff = 0;
    for (int w = 0; w < wid; ++w) woff += wsH[w];
    int excl = woff + (s - tsum);
    #pragma unroll
    for (int k = 0; k < 4; ++k) {
        int i = t * 4 + k;
        if (i < NB) {
            base[i] = excl; cur[i] = excl;
            if (i == NB - 1) base[NB] = excl + v[k];
            excl += v[k];
        }
    }
    if (t == 0) rowstart[N] = Etot;
}

// ---------------- partition: bin edges by dst bucket, burst writes per (block,bin)
// packs each edge as (dstLocal<<25)|src  (src < 2^25, dstLocal < 128)
__global__ __launch_bounds__(256) void partition_kernel(
    const int* __restrict__ ei, int* __restrict__ bucketCur,
    unsigned* __restrict__ ebuf, int E, int Etot, int NB)
{
    __shared__ int lcnt[NB_MAX];
    __shared__ int lbase[NB_MAX];
    int t = threadIdx.x;
    for (int i = t; i < NB; i += 256) lcnt[i] = 0;
    __syncthreads();
    int base = blockIdx.x * TILE;
    for (int k = t; k < TILE; k += 256) {
        int e = base + k;
        if (e < Etot) {
            int dst = (e < E) ? ei[E + e] : (e - E);
            atomicAdd(&lcnt[dst >> 7], 1);
        }
    }
    __syncthreads();
    for (int i = t; i < NB; i += 256) {
        int c = lcnt[i];
        lbase[i] = c ? atomicAdd(&bucketCur[i], c) : 0;
    }
    __syncthreads();
    for (int i = t; i < NB; i += 256) lcnt[i] = 0;   // reuse as local rank cursor
    __syncthreads();
    for (int k = t; k < TILE; k += 256) {
        int e = base + k;
        if (e < Etot) {
            int src, dst;
            if (e < E) { src = ei[e]; dst = ei[E + e]; }
            else       { src = dst = e - E; }
            int b = dst >> 7;
            int r = atomicAdd(&lcnt[b], 1);
            ebuf[lbase[b] + r] = ((unsigned)(dst & (B_N - 1)) << 25) | (unsigned)src;
        }
    }
}

// ---------------- per-bucket counting sort -> esrc sorted by node + rowstart
__global__ __launch_bounds__(256) void bucket_sort_kernel(
    const unsigned* __restrict__ ebuf, const int* __restrict__ bucketBase,
    int* __restrict__ rowstart, int* __restrict__ esrc, int N)
{
    __shared__ int lhist[B_N];
    __shared__ int lstart[B_N];
    __shared__ int wsum1;
    int blk = blockIdx.x, t = threadIdx.x;
    int e0 = bucketBase[blk], e1 = bucketBase[blk + 1];
    if (t < B_N) lhist[t] = 0;
    __syncthreads();
    for (int k = e0 + t; k < e1; k += 256)
        atomicAdd(&lhist[ebuf[k] >> 25], 1);
    __syncthreads();
    int lane = t & 63;
    if (t < B_N) {                       // inclusive scan over 2 waves
        int s = lhist[t];
        for (int off = 1; off < 64; off <<= 1) {
            int u = __shfl_up(s, off);
            if (lane >= off) s += u;
        }
        lstart[t] = s;
        if (t == 63) wsum1 = s;          // total of wave 0
    }
    __syncthreads();
    if (t < B_N) {
        int s = lstart[t];
        if (t >= 64) s += wsum1;
        int excl = s - lhist[t];
        lstart[t] = excl;
        int n = blk * B_N + t;
        if (n < N) rowstart[n] = e0 + excl;
    }
    __syncthreads();
    if (t < B_N) lhist[t] = 0;           // reuse as rank cursor
    __syncthreads();
    for (int k = e0 + t; k < e1; k += 256) {
        unsigned pk = ebuf[k];
        int d = pk >> 25;
        int r = atomicAdd(&lhist[d], 1);
        esrc[e0 + lstart[d] + r] = (int)(pk & 0x1FFFFFF);
    }
}

// ---------------- Layer 1 aggregation: wave per dst; lane = eo*32+c2 handles
// channels {2c2,2c2+1} of edge-parity eo. 4 edges in flight.
__global__ __launch_bounds__(256) void agg1_kernel(
    const int* __restrict__ esrc, const int* __restrict__ rowstart,
    const float* __restrict__ hp, const __half* __restrict__ a_src1,
    const float* __restrict__ a_dst1, const float* __restrict__ b1,
    __half* __restrict__ h2, int N)
{
    int wglobal = (blockIdx.x * 256 + threadIdx.x) >> 6;
    int nwaves = (gridDim.x * 256) >> 6;
    int lane = threadIdx.x & 63;
    int c2 = lane & 31, eo = lane >> 5;
    int h = c2 >> 2;                      // head of channels 2c2,2c2+1
    for (int n = wglobal; n < N; n += nwaves) {
        int end = rowstart[n + 1];
        float ad = a_dst1[n * 8 + h];
        float ax = 0.f, ay = 0.f, wsum = 0.f;
        int p = rowstart[n] + eo;
        for (; p + 6 < end; p += 8) {        // 4 edges in flight per lane
            int s0 = esrc[p], s1 = esrc[p + 2], s2 = esrc[p + 4], s3 = esrc[p + 6];
            float a0 = __half2float(a_src1[s0 * 8 + h]) + ad;
            float a1 = __half2float(a_src1[s1 * 8 + h]) + ad;
            float a2 = __half2float(a_src1[s2 * 8 + h]) + ad;
            float a3 = __half2float(a_src1[s3 * 8 + h]) + ad;
            __half2 q0 = ((const __half2*)(hp + (size_t)s0 * 32))[c2];
            __half2 q1 = ((const __half2*)(hp + (size_t)s1 * 32))[c2];
            __half2 q2 = ((const __half2*)(hp + (size_t)s2 * 32))[c2];
            __half2 q3 = ((const __half2*)(hp + (size_t)s3 * 32))[c2];
            a0 = (a0 > 0.f) ? a0 : NEG * a0;
            a1 = (a1 > 0.f) ? a1 : NEG * a1;
            a2 = (a2 > 0.f) ? a2 : NEG * a2;
            a3 = (a3 > 0.f) ? a3 : NEG * a3;
            float w0 = __expf(a0), w1 = __expf(a1), w2 = __expf(a2), w3 = __expf(a3);
            ax = fmaf(w0, __low2float(q0), ax);  ay = fmaf(w0, __high2float(q0), ay);
            ax = fmaf(w1, __low2float(q1), ax);  ay = fmaf(w1, __high2float(q1), ay);
            ax = fmaf(w2, __low2float(q2), ax);  ay = fmaf(w2, __high2float(q2), ay);
            ax = fmaf(w3, __low2float(q3), ax);  ay = fmaf(w3, __high2float(q3), ay);
            wsum += (w0 + w1) + (w2 + w3);
        }
        for (; p < end; p += 2) {
            int s0 = esrc[p];
            float a0 = __half2float(a_src1[s0 * 8 + h]) + ad;
            __half2 q0 = ((const __half2*)(hp + (size_t)s0 * 32))[c2];
            a0 = (a0 > 0.f) ? a0 : NEG * a0;
            float w0 = __expf(a0);
            ax = fmaf(w0, __low2float(q0), ax);
            ay = fmaf(w0, __high2float(q0), ay);
            wsum += w0;
        }
        ax += __shfl_xor(ax, 32);
        ay += __shfl_xor(ay, 32);
        wsum += __shfl_xor(wsum, 32);
        if (eo == 0) {
            float inv = 1.f / (wsum + GAT_EPS);
            float2 bb = *(const float2*)(b1 + 2 * c2);
            float vx = fmaf(ax, inv, bb.x);
            float vy = fmaf(ay, inv, bb.y);
            vx = vx > 0.f ? vx : 0.f;
            vy = vy > 0.f ? vy : 0.f;
            ((__half2*)(h2 + (size_t)n * 64))[c2] =
                __halves2half2(__float2half(vx), __float2half(vy));
        }
    }
}

// ---------------- Layer 2 GEMM (MFMA): h2(fp16)[N,64] @ W2[64,16] -> h2w fp16[N,16]
// + a_src2[N], a_dst2[N]. One wave per 16-node tile: 2 MFMAs (K=64).
__global__ __launch_bounds__(256) void gemm2_kernel(
    const __half* __restrict__ h2, const float* __restrict__ W2,
    const float* __restrict__ att_s2, const float* __restrict__ att_d2,
    __half* __restrict__ h2w, float* __restrict__ a_src2, float* __restrict__ a_dst2, int N)
{
    __shared__ _Float16 bfrag[2 * 512];   // 2 KB: frag k0, lane l, elem j
    __shared__ float cs[4][16 * 20];      // per-wave C staging, padded stride 20
    int tid = threadIdx.x;
    for (int idx = tid; idx < 1024; idx += 256) {
        int f = idx >> 9, l = (idx >> 3) & 63, j = idx & 7;
        int row = f * 32 + ((l >> 4) << 3) + j;   // same k-map as A-pack
        int col = l & 15;
        bfrag[idx] = (_Float16)W2[row * 16 + col];
    }
    __syncthreads();
    int lane = tid & 63, wid = tid >> 6;
    int mrow = lane & 15, kgrp = lane >> 4;
    float* csw = &cs[wid][0];
    const half8* bf8 = (const half8*)bfrag;
    int ech = (lane & 3) << 2;            // epilogue channel block
    float as0 = att_s2[ech], as1 = att_s2[ech + 1], as2 = att_s2[ech + 2], as3 = att_s2[ech + 3];
    float ad0 = att_d2[ech], ad1 = att_d2[ech + 1], ad2 = att_d2[ech + 2], ad3 = att_d2[ech + 3];
    int ntiles = (N + 15) >> 4;
    for (int tile = (blockIdx.x << 2) + wid; tile < ntiles; tile += (gridDim.x << 2)) {
        int n0 = tile << 4;
        f32x4 acc = {0, 0, 0, 0};
        int arow = n0 + mrow; if (arow >= N) arow = N - 1;
        const half8* h2r = (const half8*)(h2 + (size_t)arow * 64 + (kgrp << 3));
        acc = __builtin_amdgcn_mfma_f32_16x16x32_f16(h2r[0], bf8[lane], acc, 0, 0, 0);
        acc = __builtin_amdgcn_mfma_f32_16x16x32_f16(h2r[4], bf8[64 + lane], acc, 0, 0, 0);
        #pragma unroll
        for (int r = 0; r < 4; ++r)
            csw[((kgrp << 2) + r) * 20 + mrow] = acc[r];
        asm volatile("s_waitcnt lgkmcnt(0)" ::: "memory");
        int node = lane >> 2;
        int n = n0 + node;
        if (n < N) {
            float4 v = *(const float4*)&csw[node * 20 + ech];
            unsigned pk0 = f2h(v.x) | (f2h(v.y) << 16);
            unsigned pk1 = f2h(v.z) | (f2h(v.w) << 16);
            *(int2*)((char*)(h2w + (size_t)n * 16) + (ech << 1)) = make_int2((int)pk0, (int)pk1);
            float s = fmaf(v.x, as0, fmaf(v.y, as1, fmaf(v.z, as2, v.w * as3)));
            float d = fmaf(v.x, ad0, fmaf(v.y, ad1, fmaf(v.z, ad2, v.w * ad3)));
            s += __shfl_xor(s, 1); d += __shfl_xor(d, 1);
            s += __shfl_xor(s, 2); d += __shfl_xor(d, 2);
            if ((lane & 3) == 0) { a_src2[n] = s; a_dst2[n] = d; }
        }
    }
}

// ---------------- Layer 2 aggregation: wave per dst; lane = eo*8+c2, 8 edges/iter
__global__ __launch_bounds__(256) void agg2_kernel(
    const int* __restrict__ esrc, const int* __restrict__ rowstart,
    const __half* __restrict__ h2w, const float* __restrict__ a_src2,
    const float* __restrict__ a_dst2, const float* __restrict__ b2,
    float* __restrict__ out, int N)
{
    int wglobal = (blockIdx.x * 256 + threadIdx.x) >> 6;
    int nwaves = (gridDim.x * 256) >> 6;
    int lane = threadIdx.x & 63;
    int c2 = lane & 7, eo = lane >> 3;
    for (int n = wglobal; n < N; n += nwaves) {
        int start = rowstart[n], end = rowstart[n + 1];
        float ad = a_dst2[n];
        float ax = 0.f, ay = 0.f, wsum = 0.f;
        for (int p = start + eo; p < end; p += 8) {
            int s = esrc[p];
            float a = a_src2[s] + ad;
            __half2 q = ((const __half2*)(h2w + (size_t)s * 16))[c2];
            a = (a > 0.f) ? a : NEG * a;
            float w = __expf(a);
            ax = fmaf(w, __low2float(q), ax);
            ay = fmaf(w, __high2float(q), ay);
            wsum += w;
        }
        ax += __shfl_xor(ax, 8);  ay += __shfl_xor(ay, 8);  wsum += __shfl_xor(wsum, 8);
        ax += __shfl_xor(ax, 16); ay += __shfl_xor(ay, 16); wsum += __shfl_xor(wsum, 16);
        ax += __shfl_xor(ax, 32); ay += __shfl_xor(ay, 32); wsum += __shfl_xor(wsum, 32);
        if (eo == 0) {
            float inv = 1.f / (wsum + GAT_EPS);
            float2 bb = *(const float2*)(b2 + 2 * c2);
            float2 o;
            o.x = fmaf(ax, inv, bb.x);
            o.y = fmaf(ay, inv, bb.y);
            o.x = o.x > 0.f ? o.x : 0.f;
            o.y = o.y > 0.f ? o.y : 0.f;
            ((float2*)(out + (size_t)n * 16))[c2] = o;
        }
    }
}

extern "C" void kernel_launch(void* const* d_in, const int* in_sizes, int n_in,
                              void* d_out, int out_size, void* d_ws, size_t ws_size,
                              hipStream_t stream)
{
    const float* x      = (const float*)d_in[0];
    const int*   ei     = (const int*)  d_in[1];   // [2,E] int32
    const float* W1     = (const float*)d_in[2];
    const float* att_s1 = (const float*)d_in[3];
    const float* att_d1 = (const float*)d_in[4];
    const float* b1     = (const float*)d_in[5];
    const float* W2     = (const float*)d_in[6];
    const float* att_s2 = (const float*)d_in[7];
    const float* att_d2 = (const float*)d_in[8];
    const float* b2     = (const float*)d_in[9];
    float* out = (float*)d_out;

    int N = in_sizes[0] / IN_C;
    int E = in_sizes[1] / 2;
    int Etot = E + N;
    int NB = (N + B_N - 1) / B_N;      // 782 for N=100000 (<= NB_MAX)

    // workspace: floats, then ints. ebuf now has its OWN region (K1 overlaps CSR).
    float* ws = (float*)d_ws;
    float*  hp      = ws;                               // N*32 (fp16 h, 128 B rows)
    __half* a_src1  = (__half*)(hp + (size_t)N * 32);   // N*8 halves = N*4 floats
    float*  a_dst1  = (float*)a_src1 + (size_t)N * 4;   // N*8
    __half* h2      = (__half*)(a_dst1 + (size_t)N * 8);// N*64 halves = N*32 floats
    __half* h2w     = (__half*)((float*)h2 + (size_t)N * 32); // N*16 halves = N*8 floats
    float*  a_src2  = (float*)h2w + (size_t)N * 8;      // N
    float*  a_dst2  = a_src2 + (size_t)N;               // N
    int* rowstart   = (int*)(a_dst2 + (size_t)N);       // N+1
    int* bucketCnt  = rowstart   + (N + 1);             // NB_MAX
    int* bucketBase = bucketCnt  + NB_MAX;              // NB_MAX+1
    int* bucketCur  = bucketBase + NB_MAX + 1;          // NB_MAX
    int* esrc       = bucketCur  + NB_MAX;              // Etot
    unsigned* ebuf  = (unsigned*)(esrc + Etot);         // Etot (own region)

    int egrid = (Etot + TILE - 1) / TILE;

    hipMemsetAsync(bucketCnt, 0, NB_MAX * sizeof(int), stream);
    // K1: gemm1 + bucket_count fused (independent work, disjoint block ranges)
    k1_kernel<<<GEMM_BLKS + egrid, 256, 0, stream>>>(
        x, W1, att_s1, att_d1, hp, a_src1, a_dst1, ei, bucketCnt, E, Etot, NB, N);
    bucket_scan_kernel<<<1, 256, 0, stream>>>(bucketCnt, bucketBase, bucketCur,
                                              rowstart, NB, N, Etot);
    partition_kernel<<<egrid, 256, 0, stream>>>(ei, bucketCur, ebuf, E, Etot, NB);
    bucket_sort_kernel<<<NB, 256, 0, stream>>>(ebuf, bucketBase, rowstart, esrc, N);

    agg1_kernel<<<2048, 256, 0, stream>>>(esrc, rowstart, hp, a_src1, a_dst1, b1, h2, N);

    gemm2_kernel<<<1024, 256, 0, stream>>>(h2, W2, att_s2, att_d2, h2w, a_src2, a_dst2, N);
    agg2_kernel<<<1024, 256, 0, stream>>>(esrc, rowstart, h2w, a_src2, a_dst2, b2, out, N);
}

// Round 12
// 176.427 us; speedup vs baseline: 6.8065x; 1.1908x over previous
//
#include <hip/hip_runtime.h>
#include <hip/hip_fp16.h>

#define IN_C 128
#define NEG 0.2f
#define GAT_EPS 1e-16f
#define B_N 128            // dst nodes per bucket (dstLocal fits in 7 bits)
#define NB_MAX 1024        // supports N <= 131072
#define TILE 8192          // edges per partition block
#define GEMM_BLKS 1024     // gemm1 blocks inside fused K1

typedef _Float16 half8 __attribute__((ext_vector_type(8)));
typedef float f32x4 __attribute__((ext_vector_type(4)));

static __device__ inline unsigned f2h(float f) {
    _Float16 h = (_Float16)f;
    unsigned short u;
    __builtin_memcpy(&u, &h, 2);
    return (unsigned)u;
}

// ---------------- Fused K1: gemm1 (MFMA) on blocks [0,GEMM_BLKS) +
// bucket histogram on blocks [GEMM_BLKS, GEMM_BLKS+egrid).
// gemm1: x[N,128] @ W1[128,64] -> hp fp16[N,64] (128 B rows) + a_src1 fp16[N,8] + a_dst1 fp32[N,8]
__global__ __launch_bounds__(256) void k1_kernel(
    const float* __restrict__ x, const float* __restrict__ W1,
    const float* __restrict__ att_s1, const float* __restrict__ att_d1,
    float* __restrict__ hp, __half* __restrict__ a_src1, float* __restrict__ a_dst1,
    const int* __restrict__ ei, int* __restrict__ bucketCnt,
    int E, int Etot, int NB, int N)
{
    __shared__ __align__(16) char smem[34304];   // 16K bfrag + 17K cs + 512B att
    int tid = threadIdx.x;

    if ((int)blockIdx.x >= GEMM_BLKS) {
        // ---- bucket_count branch ----
        int* hist = (int*)smem;
        for (int i = tid; i < NB; i += 256) hist[i] = 0;
        __syncthreads();
        int base = ((int)blockIdx.x - GEMM_BLKS) * TILE;
        for (int k = tid; k < TILE; k += 256) {
            int e = base + k;
            if (e < Etot) {
                int dst = (e < E) ? ei[E + e] : (e - E);   // self-loops appended
                atomicAdd(&hist[dst >> 7], 1);
            }
        }
        __syncthreads();
        for (int i = tid; i < NB; i += 256)
            if (hist[i]) atomicAdd(&bucketCnt[i], hist[i]);
        return;
    }

    // ---- gemm1 branch ----
    _Float16* bfrag = (_Float16*)smem;                   // 16 KB
    float* csbase   = (float*)(smem + 16384);            // 4 waves x 16x68
    float* attS     = (float*)(smem + 16384 + 17408);
    float* attD     = attS + 64;
    if (tid < 64) { attS[tid] = att_s1[tid]; attD[tid] = att_d1[tid]; }
    // B frags: f=(k0*4+nt); lane holds W1[k0*32+(l>>4)*8+j][nt*16+(l&15)]
    // (k-map only needs to match the A-pack's k-map.)
    for (int idx = tid; idx < 8192; idx += 256) {
        int f = idx >> 9;
        int l = (idx >> 3) & 63;
        int j = idx & 7;
        int k0 = f >> 2, nt = f & 3;
        int row = k0 * 32 + ((l >> 4) << 3) + j;
        int col = (nt << 4) + (l & 15);
        bfrag[idx] = (_Float16)W1[row * 64 + col];
    }
    __syncthreads();

    int lane = tid & 63, wid = tid >> 6;
    float* csw = csbase + wid * (16 * 68);
    int mrow = lane & 15;          // node row within tile
    int kgrp = lane >> 4;          // k sub-group
    const half8* bf8 = (const half8*)bfrag;
    int ntiles = (N + 15) >> 4;
    for (int tile = ((int)blockIdx.x << 2) + wid; tile < ntiles; tile += (GEMM_BLKS << 2)) {
        int n0 = tile << 4;
        f32x4 acc0 = {0,0,0,0}, acc1 = {0,0,0,0}, acc2 = {0,0,0,0}, acc3 = {0,0,0,0};
        int arow = n0 + mrow; if (arow >= N) arow = N - 1;
        const float* xr = x + (size_t)arow * IN_C + (kgrp << 3);
        #pragma unroll
        for (int k0 = 0; k0 < 4; ++k0) {
            float4 xa = *(const float4*)(xr + k0 * 32);
            float4 xb = *(const float4*)(xr + k0 * 32 + 4);
            half8 a;
            a[0] = (_Float16)xa.x; a[1] = (_Float16)xa.y;
            a[2] = (_Float16)xa.z; a[3] = (_Float16)xa.w;
            a[4] = (_Float16)xb.x; a[5] = (_Float16)xb.y;
            a[6] = (_Float16)xb.z; a[7] = (_Float16)xb.w;
            acc0 = __builtin_amdgcn_mfma_f32_16x16x32_f16(a, bf8[(k0 * 4 + 0) * 64 + lane], acc0, 0, 0, 0);
            acc1 = __builtin_amdgcn_mfma_f32_16x16x32_f16(a, bf8[(k0 * 4 + 1) * 64 + lane], acc1, 0, 0, 0);
            acc2 = __builtin_amdgcn_mfma_f32_16x16x32_f16(a, bf8[(k0 * 4 + 2) * 64 + lane], acc2, 0, 0, 0);
            acc3 = __builtin_amdgcn_mfma_f32_16x16x32_f16(a, bf8[(k0 * 4 + 3) * 64 + lane], acc3, 0, 0, 0);
        }
        // C/D layout: col = lane&15, row = (lane>>4)*4 + reg   [HW-verified]
        #pragma unroll
        for (int r = 0; r < 4; ++r) {
            int row = (kgrp << 2) + r;
            csw[row * 68 +  0 + mrow] = acc0[r];
            csw[row * 68 + 16 + mrow] = acc1[r];
            csw[row * 68 + 32 + mrow] = acc2[r];
            csw[row * 68 + 48 + mrow] = acc3[r];
        }
        asm volatile("s_waitcnt lgkmcnt(0)" ::: "memory");   // wave-wide LDS RAW fence
        // pass A: 16 fp16 channels per lane (node = lane>>2, quad = lane&3)
        {
            int node = lane >> 2, cq = lane & 3;
            int n = n0 + node;
            if (n < N) {
                const float* src = &csw[node * 68 + (cq << 4)];
                float4 v0 = *(const float4*)(src);
                float4 v1 = *(const float4*)(src + 4);
                float4 v2 = *(const float4*)(src + 8);
                float4 v3 = *(const float4*)(src + 12);
                unsigned pk[8];
                pk[0] = f2h(v0.x) | (f2h(v0.y) << 16);
                pk[1] = f2h(v0.z) | (f2h(v0.w) << 16);
                pk[2] = f2h(v1.x) | (f2h(v1.y) << 16);
                pk[3] = f2h(v1.z) | (f2h(v1.w) << 16);
                pk[4] = f2h(v2.x) | (f2h(v2.y) << 16);
                pk[5] = f2h(v2.z) | (f2h(v2.w) << 16);
                pk[6] = f2h(v3.x) | (f2h(v3.y) << 16);
                pk[7] = f2h(v3.z) | (f2h(v3.w) << 16);
                char* dst = (char*)(hp + (size_t)n * 32) + (cq << 5);
                ((int4*)dst)[0] = *(int4*)&pk[0];
                ((int4*)dst)[1] = *(int4*)&pk[4];
            }
        }
        // pass B: a_src/a_dst per (node, head), two half-passes
        #pragma unroll
        for (int pr = 0; pr < 2; ++pr) {
            int node = (pr << 3) + (lane >> 3), head = lane & 7;
            int n = n0 + node;
            if (n < N) {
                float s = 0.f, d = 0.f;
                #pragma unroll
                for (int c = 0; c < 8; ++c) {
                    float v = csw[node * 68 + (head << 3) + c];
                    s = fmaf(v, attS[(head << 3) + c], s);
                    d = fmaf(v, attD[(head << 3) + c], d);
                }
                a_src1[n * 8 + head] = __float2half(s);
                a_dst1[n * 8 + head] = d;
            }
        }
    }
}

// ---------------- exclusive scan of bucket counts (1 block; NB <= 1024)
__global__ __launch_bounds__(256) void bucket_scan_kernel(
    const int* __restrict__ cnt, int* __restrict__ base, int* __restrict__ cur,
    int* __restrict__ rowstart, int NB, int N, int Etot)
{
    int t = threadIdx.x;
    int v[4]; int s = 0;
    #pragma unroll
    for (int k = 0; k < 4; ++k) { int i = t * 4 + k; v[k] = (i < NB) ? cnt[i] : 0; s += v[k]; }
    int tsum = s;
    int lane = t & 63, wid = t >> 6;
    for (int off = 1; off < 64; off <<= 1) {
        int u = __shfl_up(s, off);
        if (lane >= off) s += u;
    }
    __shared__ int wsH[4];
    if (lane == 63) wsH[wid] = s;
    __syncthreads();
    int woff = 0;
    for (int w = 0; w < wid; ++w) woff += wsH[w];
    int excl = woff + (s - tsum);
    #pragma unroll
    for (int k = 0; k < 4; ++k) {
        int i = t * 4 + k;
        if (i < NB) {
            base[i] = excl; cur[i] = excl;
            if (i == NB - 1) base[NB] = excl + v[k];
            excl += v[k];
        }
    }
    if (t == 0) rowstart[N] = Etot;
}

// ---------------- partition: bin edges by dst bucket, burst writes per (block,bin)
// packs each edge as (dstLocal<<25)|src  (src < 2^25, dstLocal < 128)
__global__ __launch_bounds__(256) void partition_kernel(
    const int* __restrict__ ei, int* __restrict__ bucketCur,
    unsigned* __restrict__ ebuf, int E, int Etot, int NB)
{
    __shared__ int lcnt[NB_MAX];
    __shared__ int lbase[NB_MAX];
    int t = threadIdx.x;
    for (int i = t; i < NB; i += 256) lcnt[i] = 0;
    __syncthreads();
    int base = blockIdx.x * TILE;
    for (int k = t; k < TILE; k += 256) {
        int e = base + k;
        if (e < Etot) {
            int dst = (e < E) ? ei[E + e] : (e - E);
            atomicAdd(&lcnt[dst >> 7], 1);
        }
    }
    __syncthreads();
    for (int i = t; i < NB; i += 256) {
        int c = lcnt[i];
        lbase[i] = c ? atomicAdd(&bucketCur[i], c) : 0;
    }
    __syncthreads();
    for (int i = t; i < NB; i += 256) lcnt[i] = 0;   // reuse as local rank cursor
    __syncthreads();
    for (int k = t; k < TILE; k += 256) {
        int e = base + k;
        if (e < Etot) {
            int src, dst;
            if (e < E) { src = ei[e]; dst = ei[E + e]; }
            else       { src = dst = e - E; }
            int b = dst >> 7;
            int r = atomicAdd(&lcnt[b], 1);
            ebuf[lbase[b] + r] = ((unsigned)(dst & (B_N - 1)) << 25) | (unsigned)src;
        }
    }
}

// ---------------- per-bucket counting sort -> esrc sorted by node + rowstart
__global__ __launch_bounds__(256) void bucket_sort_kernel(
    const unsigned* __restrict__ ebuf, const int* __restrict__ bucketBase,
    int* __restrict__ rowstart, int* __restrict__ esrc, int N)
{
    __shared__ int lhist[B_N];
    __shared__ int lstart[B_N];
    __shared__ int wsum1;
    int blk = blockIdx.x, t = threadIdx.x;
    int e0 = bucketBase[blk], e1 = bucketBase[blk + 1];
    if (t < B_N) lhist[t] = 0;
    __syncthreads();
    for (int k = e0 + t; k < e1; k += 256)
        atomicAdd(&lhist[ebuf[k] >> 25], 1);
    __syncthreads();
    int lane = t & 63;
    if (t < B_N) {                       // inclusive scan over 2 waves
        int s = lhist[t];
        for (int off = 1; off < 64; off <<= 1) {
            int u = __shfl_up(s, off);
            if (lane >= off) s += u;
        }
        lstart[t] = s;
        if (t == 63) wsum1 = s;          // total of wave 0
    }
    __syncthreads();
    if (t < B_N) {
        int s = lstart[t];
        if (t >= 64) s += wsum1;
        int excl = s - lhist[t];
        lstart[t] = excl;
        int n = blk * B_N + t;
        if (n < N) rowstart[n] = e0 + excl;
    }
    __syncthreads();
    if (t < B_N) lhist[t] = 0;           // reuse as rank cursor
    __syncthreads();
    for (int k = e0 + t; k < e1; k += 256) {
        unsigned pk = ebuf[k];
        int d = pk >> 25;
        int r = atomicAdd(&lhist[d], 1);
        esrc[e0 + lstart[d] + r] = (int)(pk & 0x1FFFFFF);
    }
}

// ---------------- Layer 1 aggregation: 2 nodes per wave (32 lanes each).
// Lane c2 owns channels {2c2,2c2+1}; every lane sees every edge -> wsum is
// complete in-lane (per head h=c2>>2), zero shuffles. 4-deep edge pipeline
// per half -> 8 edges in flight per wave.
__global__ __launch_bounds__(256) void agg1_kernel(
    const int* __restrict__ esrc, const int* __restrict__ rowstart,
    const float* __restrict__ hp, const __half* __restrict__ a_src1,
    const float* __restrict__ a_dst1, const float* __restrict__ b1,
    __half* __restrict__ h2, int N)
{
    int wslot = (blockIdx.x * 256 + threadIdx.x) >> 6;
    int nw = (gridDim.x * 256) >> 6;
    int lane = threadIdx.x & 63;
    int half = lane >> 5, c2 = lane & 31;
    int h = c2 >> 2;
    for (int base = wslot * 2; base < N; base += nw * 2) {
        int n = base + half;
        bool act = (n < N);
        int nn = act ? n : 0;
        int p = rowstart[nn], end = act ? rowstart[nn + 1] : 0;
        float ad = a_dst1[nn * 8 + h];
        float ax = 0.f, ay = 0.f, wsum = 0.f;
        for (; p + 3 < end; p += 4) {
            int s0 = esrc[p], s1 = esrc[p + 1], s2 = esrc[p + 2], s3 = esrc[p + 3];
            float a0 = __half2float(a_src1[s0 * 8 + h]) + ad;
            float a1 = __half2float(a_src1[s1 * 8 + h]) + ad;
            float a2 = __half2float(a_src1[s2 * 8 + h]) + ad;
            float a3 = __half2float(a_src1[s3 * 8 + h]) + ad;
            __half2 q0 = ((const __half2*)(hp + (size_t)s0 * 32))[c2];
            __half2 q1 = ((const __half2*)(hp + (size_t)s1 * 32))[c2];
            __half2 q2 = ((const __half2*)(hp + (size_t)s2 * 32))[c2];
            __half2 q3 = ((const __half2*)(hp + (size_t)s3 * 32))[c2];
            a0 = (a0 > 0.f) ? a0 : NEG * a0;
            a1 = (a1 > 0.f) ? a1 : NEG * a1;
            a2 = (a2 > 0.f) ? a2 : NEG * a2;
            a3 = (a3 > 0.f) ? a3 : NEG * a3;
            float w0 = __expf(a0), w1 = __expf(a1), w2 = __expf(a2), w3 = __expf(a3);
            ax = fmaf(w0, __low2float(q0), ax);  ay = fmaf(w0, __high2float(q0), ay);
            ax = fmaf(w1, __low2float(q1), ax);  ay = fmaf(w1, __high2float(q1), ay);
            ax = fmaf(w2, __low2float(q2), ax);  ay = fmaf(w2, __high2float(q2), ay);
            ax = fmaf(w3, __low2float(q3), ax);  ay = fmaf(w3, __high2float(q3), ay);
            wsum += (w0 + w1) + (w2 + w3);
        }
        for (; p < end; ++p) {
            int s0 = esrc[p];
            float a0 = __half2float(a_src1[s0 * 8 + h]) + ad;
            __half2 q0 = ((const __half2*)(hp + (size_t)s0 * 32))[c2];
            a0 = (a0 > 0.f) ? a0 : NEG * a0;
            float w0 = __expf(a0);
            ax = fmaf(w0, __low2float(q0), ax);
            ay = fmaf(w0, __high2float(q0), ay);
            wsum += w0;
        }
        if (act) {
            float inv = 1.f / (wsum + GAT_EPS);
            float2 bb = *(const float2*)(b1 + 2 * c2);
            float vx = fmaf(ax, inv, bb.x);
            float vy = fmaf(ay, inv, bb.y);
            vx = vx > 0.f ? vx : 0.f;
            vy = vy > 0.f ? vy : 0.f;
            ((__half2*)(h2 + (size_t)n * 64))[c2] =
                __halves2half2(__float2half(vx), __float2half(vy));
        }
    }
}

// ---------------- Layer 2 GEMM (MFMA): h2(fp16)[N,64] @ W2[64,16] -> h2w fp16[N,16]
// + a_src2[N], a_dst2[N]. One wave per 16-node tile: 2 MFMAs (K=64).
__global__ __launch_bounds__(256) void gemm2_kernel(
    const __half* __restrict__ h2, const float* __restrict__ W2,
    const float* __restrict__ att_s2, const float* __restrict__ att_d2,
    __half* __restrict__ h2w, float* __restrict__ a_src2, float* __restrict__ a_dst2, int N)
{
    __shared__ _Float16 bfrag[2 * 512];   // 2 KB: frag k0, lane l, elem j
    __shared__ float cs[4][16 * 20];      // per-wave C staging, padded stride 20
    int tid = threadIdx.x;
    for (int idx = tid; idx < 1024; idx += 256) {
        int f = idx >> 9, l = (idx >> 3) & 63, j = idx & 7;
        int row = f * 32 + ((l >> 4) << 3) + j;   // same k-map as A-pack
        int col = l & 15;
        bfrag[idx] = (_Float16)W2[row * 16 + col];
    }
    __syncthreads();
    int lane = tid & 63, wid = tid >> 6;
    int mrow = lane & 15, kgrp = lane >> 4;
    float* csw = &cs[wid][0];
    const half8* bf8 = (const half8*)bfrag;
    int ech = (lane & 3) << 2;            // epilogue channel block
    float as0 = att_s2[ech], as1 = att_s2[ech + 1], as2 = att_s2[ech + 2], as3 = att_s2[ech + 3];
    float ad0 = att_d2[ech], ad1 = att_d2[ech + 1], ad2 = att_d2[ech + 2], ad3 = att_d2[ech + 3];
    int ntiles = (N + 15) >> 4;
    for (int tile = (blockIdx.x << 2) + wid; tile < ntiles; tile += (gridDim.x << 2)) {
        int n0 = tile << 4;
        f32x4 acc = {0, 0, 0, 0};
        int arow = n0 + mrow; if (arow >= N) arow = N - 1;
        const half8* h2r = (const half8*)(h2 + (size_t)arow * 64 + (kgrp << 3));
        acc = __builtin_amdgcn_mfma_f32_16x16x32_f16(h2r[0], bf8[lane], acc, 0, 0, 0);
        acc = __builtin_amdgcn_mfma_f32_16x16x32_f16(h2r[4], bf8[64 + lane], acc, 0, 0, 0);
        #pragma unroll
        for (int r = 0; r < 4; ++r)
            csw[((kgrp << 2) + r) * 20 + mrow] = acc[r];
        asm volatile("s_waitcnt lgkmcnt(0)" ::: "memory");
        int node = lane >> 2;
        int n = n0 + node;
        if (n < N) {
            float4 v = *(const float4*)&csw[node * 20 + ech];
            unsigned pk0 = f2h(v.x) | (f2h(v.y) << 16);
            unsigned pk1 = f2h(v.z) | (f2h(v.w) << 16);
            *(int2*)((char*)(h2w + (size_t)n * 16) + (ech << 1)) = make_int2((int)pk0, (int)pk1);
            float s = fmaf(v.x, as0, fmaf(v.y, as1, fmaf(v.z, as2, v.w * as3)));
            float d = fmaf(v.x, ad0, fmaf(v.y, ad1, fmaf(v.z, ad2, v.w * ad3)));
            s += __shfl_xor(s, 1); d += __shfl_xor(d, 1);
            s += __shfl_xor(s, 2); d += __shfl_xor(d, 2);
            if ((lane & 3) == 0) { a_src2[n] = s; a_dst2[n] = d; }
        }
    }
}

// ---------------- Layer 2 aggregation: 8 nodes per wave (8 lanes each).
// Lane c2 owns channels {2c2,2c2+1}; wsum complete in-lane, zero shuffles.
// 4-deep pipeline per group -> 32 edges in flight per wave.
__global__ __launch_bounds__(256) void agg2_kernel(
    const int* __restrict__ esrc, const int* __restrict__ rowstart,
    const __half* __restrict__ h2w, const float* __restrict__ a_src2,
    const float* __restrict__ a_dst2, const float* __restrict__ b2,
    float* __restrict__ out, int N)
{
    int wslot = (blockIdx.x * 256 + threadIdx.x) >> 6;
    int nw = (gridDim.x * 256) >> 6;
    int lane = threadIdx.x & 63;
    int oct = lane >> 3, c2 = lane & 7;
    for (int base = wslot * 8; base < N; base += nw * 8) {
        int n = base + oct;
        bool act = (n < N);
        int nn = act ? n : 0;
        int p = rowstart[nn], end = act ? rowstart[nn + 1] : 0;
        float ad = a_dst2[nn];
        float ax = 0.f, ay = 0.f, wsum = 0.f;
        for (; p + 3 < end; p += 4) {
            int s0 = esrc[p], s1 = esrc[p + 1], s2 = esrc[p + 2], s3 = esrc[p + 3];
            float a0 = a_src2[s0] + ad;
            float a1 = a_src2[s1] + ad;
            float a2 = a_src2[s2] + ad;
            float a3 = a_src2[s3] + ad;
            __half2 q0 = ((const __half2*)(h2w + (size_t)s0 * 16))[c2];
            __half2 q1 = ((const __half2*)(h2w + (size_t)s1 * 16))[c2];
            __half2 q2 = ((const __half2*)(h2w + (size_t)s2 * 16))[c2];
            __half2 q3 = ((const __half2*)(h2w + (size_t)s3 * 16))[c2];
            a0 = (a0 > 0.f) ? a0 : NEG * a0;
            a1 = (a1 > 0.f) ? a1 : NEG * a1;
            a2 = (a2 > 0.f) ? a2 : NEG * a2;
            a3 = (a3 > 0.f) ? a3 : NEG * a3;
            float w0 = __expf(a0), w1 = __expf(a1), w2 = __expf(a2), w3 = __expf(a3);
            ax = fmaf(w0, __low2float(q0), ax);  ay = fmaf(w0, __high2float(q0), ay);
            ax = fmaf(w1, __low2float(q1), ax);  ay = fmaf(w1, __high2float(q1), ay);
            ax = fmaf(w2, __low2float(q2), ax);  ay = fmaf(w2, __high2float(q2), ay);
            ax = fmaf(w3, __low2float(q3), ax);  ay = fmaf(w3, __high2float(q3), ay);
            wsum += (w0 + w1) + (w2 + w3);
        }
        for (; p < end; ++p) {
            int s0 = esrc[p];
            float a0 = a_src2[s0] + ad;
            __half2 q0 = ((const __half2*)(h2w + (size_t)s0 * 16))[c2];
            a0 = (a0 > 0.f) ? a0 : NEG * a0;
            float w0 = __expf(a0);
            ax = fmaf(w0, __low2float(q0), ax);
            ay = fmaf(w0, __high2float(q0), ay);
            wsum += w0;
        }
        if (act) {
            float inv = 1.f / (wsum + GAT_EPS);
            float2 bb = *(const float2*)(b2 + 2 * c2);
            float2 o;
            o.x = fmaf(ax, inv, bb.x);
            o.y = fmaf(ay, inv, bb.y);
            o.x = o.x > 0.f ? o.x : 0.f;
            o.y = o.y > 0.f ? o.y : 0.f;
            ((float2*)(out + (size_t)n * 16))[c2] = o;
        }
    }
}

extern "C" void kernel_launch(void* const* d_in, const int* in_sizes, int n_in,
                              void* d_out, int out_size, void* d_ws, size_t ws_size,
                              hipStream_t stream)
{
    const float* x      = (const float*)d_in[0];
    const int*   ei     = (const int*)  d_in[1];   // [2,E] int32
    const float* W1     = (const float*)d_in[2];
    const float* att_s1 = (const float*)d_in[3];
    const float* att_d1 = (const float*)d_in[4];
    const float* b1     = (const float*)d_in[5];
    const float* W2     = (const float*)d_in[6];
    const float* att_s2 = (const float*)d_in[7];
    const float* att_d2 = (const float*)d_in[8];
    const float* b2     = (const float*)d_in[9];
    float* out = (float*)d_out;

    int N = in_sizes[0] / IN_C;
    int E = in_sizes[1] / 2;
    int Etot = E + N;
    int NB = (N + B_N - 1) / B_N;      // 782 for N=100000 (<= NB_MAX)

    // workspace: floats, then ints. ebuf has its own region (K1 overlaps CSR).
    float* ws = (float*)d_ws;
    float*  hp      = ws;                               // N*32 (fp16 h, 128 B rows)
    __half* a_src1  = (__half*)(hp + (size_t)N * 32);   // N*8 halves = N*4 floats
    float*  a_dst1  = (float*)a_src1 + (size_t)N * 4;   // N*8
    __half* h2      = (__half*)(a_dst1 + (size_t)N * 8);// N*64 halves = N*32 floats
    __half* h2w     = (__half*)((float*)h2 + (size_t)N * 32); // N*16 halves = N*8 floats
    float*  a_src2  = (float*)h2w + (size_t)N * 8;      // N
    float*  a_dst2  = a_src2 + (size_t)N;               // N
    int* rowstart   = (int*)(a_dst2 + (size_t)N);       // N+1
    int* bucketCnt  = rowstart   + (N + 1);             // NB_MAX
    int* bucketBase = bucketCnt  + NB_MAX;              // NB_MAX+1
    int* bucketCur  = bucketBase + NB_MAX + 1;          // NB_MAX
    int* esrc       = bucketCur  + NB_MAX;              // Etot
    unsigned* ebuf  = (unsigned*)(esrc + Etot);         // Etot (own region)

    int egrid = (Etot + TILE - 1) / TILE;

    hipMemsetAsync(bucketCnt, 0, NB_MAX * sizeof(int), stream);
    // K1: gemm1 + bucket_count fused (independent work, disjoint block ranges)
    k1_kernel<<<GEMM_BLKS + egrid, 256, 0, stream>>>(
        x, W1, att_s1, att_d1, hp, a_src1, a_dst1, ei, bucketCnt, E, Etot, NB, N);
    bucket_scan_kernel<<<1, 256, 0, stream>>>(bucketCnt, bucketBase, bucketCur,
                                              rowstart, NB, N, Etot);
    partition_kernel<<<egrid, 256, 0, stream>>>(ei, bucketCur, ebuf, E, Etot, NB);
    bucket_sort_kernel<<<NB, 256, 0, stream>>>(ebuf, bucketBase, rowstart, esrc, N);

    agg1_kernel<<<2048, 256, 0, stream>>>(esrc, rowstart, hp, a_src1, a_dst1, b1, h2, N);

    gemm2_kernel<<<1024, 256, 0, stream>>>(h2, W2, att_s2, att_d2, h2w, a_src2, a_dst2, N);
    agg2_kernel<<<1024, 256, 0, stream>>>(esrc, rowstart, h2w, a_src2, a_dst2, b2, out, N);
}

// Round 13
// 170.559 us; speedup vs baseline: 7.0407x; 1.0344x over previous
//
#include <hip/hip_runtime.h>
#include <hip/hip_fp16.h>

#define IN_C 128
#define NEG 0.2f
#define GAT_EPS 1e-16f
#define B_N 128            // dst nodes per bucket (dstLocal fits in 7 bits)
#define NB_MAX 1024        // supports N <= 131072
#define TILE 8192          // edges per partition block
#define GEMM_BLKS 768      // gemm1 blocks inside fused K2 (768 + egrid <= 1024 resident)

typedef _Float16 half8 __attribute__((ext_vector_type(8)));
typedef float f32x4 __attribute__((ext_vector_type(4)));

static __device__ inline unsigned f2h(float f) {
    _Float16 h = (_Float16)f;
    unsigned short u;
    __builtin_memcpy(&u, &h, 2);
    return (unsigned)u;
}

// ---------------- bucket histogram (bin = dst >> 7)
__global__ __launch_bounds__(256) void bucket_count_kernel(
    const int* __restrict__ ei, int* __restrict__ bucketCnt, int E, int Etot, int NB)
{
    __shared__ int hist[NB_MAX];
    int t = threadIdx.x;
    for (int i = t; i < NB; i += 256) hist[i] = 0;
    __syncthreads();
    int base = blockIdx.x * TILE;
    for (int k = t; k < TILE; k += 256) {
        int e = base + k;
        if (e < Etot) {
            int dst = (e < E) ? ei[E + e] : (e - E);   // self-loops appended
            atomicAdd(&hist[dst >> 7], 1);
        }
    }
    __syncthreads();
    for (int i = t; i < NB; i += 256)
        if (hist[i]) atomicAdd(&bucketCnt[i], hist[i]);
}

// ---------------- exclusive scan of bucket counts (1 block; NB <= 1024)
__global__ __launch_bounds__(256) void bucket_scan_kernel(
    const int* __restrict__ cnt, int* __restrict__ base, int* __restrict__ cur,
    int* __restrict__ rowstart, int NB, int N, int Etot)
{
    int t = threadIdx.x;
    int v[4]; int s = 0;
    #pragma unroll
    for (int k = 0; k < 4; ++k) { int i = t * 4 + k; v[k] = (i < NB) ? cnt[i] : 0; s += v[k]; }
    int tsum = s;
    int lane = t & 63, wid = t >> 6;
    for (int off = 1; off < 64; off <<= 1) {
        int u = __shfl_up(s, off);
        if (lane >= off) s += u;
    }
    __shared__ int wsH[4];
    if (lane == 63) wsH[wid] = s;
    __syncthreads();
    int woff = 0;
    for (int w = 0; w < wid; ++w) woff += wsH[w];
    int excl = woff + (s - tsum);
    #pragma unroll
    for (int k = 0; k < 4; ++k) {
        int i = t * 4 + k;
        if (i < NB) {
            base[i] = excl; cur[i] = excl;
            if (i == NB - 1) base[NB] = excl + v[k];
            excl += v[k];
        }
    }
    if (t == 0) rowstart[N] = Etot;
}

// ---------------- Fused K2: partition on blocks [0,egrid) + gemm1 (MFMA) on
// blocks [egrid, egrid+GEMM_BLKS). Partition blocks dispatched FIRST so both
// phases are co-resident (768+208 <= 1024 slots at 4 blk/CU).
__global__ __launch_bounds__(256) void k2_kernel(
    const float* __restrict__ x, const float* __restrict__ W1,
    const float* __restrict__ att_s1, const float* __restrict__ att_d1,
    float* __restrict__ hp, __half* __restrict__ a_src1, float* __restrict__ a_dst1,
    const int* __restrict__ ei, int* __restrict__ bucketCur, unsigned* __restrict__ ebuf,
    int E, int Etot, int NB, int N, int egrid)
{
    __shared__ __align__(16) char smem[34304];   // gemm: 16K bfrag+17K cs+512B att; part: 8K
    int tid = threadIdx.x;

    if ((int)blockIdx.x < egrid) {
        // ---- partition branch: bin edges by dst bucket, burst writes ----
        int* lcnt  = (int*)smem;           // NB_MAX
        int* lbase = lcnt + NB_MAX;        // NB_MAX
        for (int i = tid; i < NB; i += 256) lcnt[i] = 0;
        __syncthreads();
        int base = (int)blockIdx.x * TILE;
        for (int k = tid; k < TILE; k += 256) {
            int e = base + k;
            if (e < Etot) {
                int dst = (e < E) ? ei[E + e] : (e - E);
                atomicAdd(&lcnt[dst >> 7], 1);
            }
        }
        __syncthreads();
        for (int i = tid; i < NB; i += 256) {
            int c = lcnt[i];
            lbase[i] = c ? atomicAdd(&bucketCur[i], c) : 0;
        }
        __syncthreads();
        for (int i = tid; i < NB; i += 256) lcnt[i] = 0;   // reuse as rank cursor
        __syncthreads();
        for (int k = tid; k < TILE; k += 256) {
            int e = base + k;
            if (e < Etot) {
                int src, dst;
                if (e < E) { src = ei[e]; dst = ei[E + e]; }
                else       { src = dst = e - E; }
                int b = dst >> 7;
                int r = atomicAdd(&lcnt[b], 1);
                ebuf[lbase[b] + r] = ((unsigned)(dst & (B_N - 1)) << 25) | (unsigned)src;
            }
        }
        return;
    }

    // ---- gemm1 branch: one wave per 16-node tile, 4 K-chunks x 4 N-tiles ----
    _Float16* bfrag = (_Float16*)smem;                   // 16 KB
    float* csbase   = (float*)(smem + 16384);            // 4 waves x 16x68
    float* attS     = (float*)(smem + 16384 + 17408);
    float* attD     = attS + 64;
    if (tid < 64) { attS[tid] = att_s1[tid]; attD[tid] = att_d1[tid]; }
    // B frags: f=(k0*4+nt); lane holds W1[k0*32+(l>>4)*8+j][nt*16+(l&15)]
    for (int idx = tid; idx < 8192; idx += 256) {
        int f = idx >> 9;
        int l = (idx >> 3) & 63;
        int j = idx & 7;
        int k0 = f >> 2, nt = f & 3;
        int row = k0 * 32 + ((l >> 4) << 3) + j;
        int col = (nt << 4) + (l & 15);
        bfrag[idx] = (_Float16)W1[row * 64 + col];
    }
    __syncthreads();

    int lane = tid & 63, wid = tid >> 6;
    float* csw = csbase + wid * (16 * 68);
    int mrow = lane & 15;
    int kgrp = lane >> 4;
    const half8* bf8 = (const half8*)bfrag;
    int ntiles = (N + 15) >> 4;
    int gb = (int)blockIdx.x - egrid;
    for (int tile = (gb << 2) + wid; tile < ntiles; tile += (GEMM_BLKS << 2)) {
        int n0 = tile << 4;
        f32x4 acc0 = {0,0,0,0}, acc1 = {0,0,0,0}, acc2 = {0,0,0,0}, acc3 = {0,0,0,0};
        int arow = n0 + mrow; if (arow >= N) arow = N - 1;
        const float* xr = x + (size_t)arow * IN_C + (kgrp << 3);
        #pragma unroll
        for (int k0 = 0; k0 < 4; ++k0) {
            float4 xa = *(const float4*)(xr + k0 * 32);
            float4 xb = *(const float4*)(xr + k0 * 32 + 4);
            half8 a;
            a[0] = (_Float16)xa.x; a[1] = (_Float16)xa.y;
            a[2] = (_Float16)xa.z; a[3] = (_Float16)xa.w;
            a[4] = (_Float16)xb.x; a[5] = (_Float16)xb.y;
            a[6] = (_Float16)xb.z; a[7] = (_Float16)xb.w;
            acc0 = __builtin_amdgcn_mfma_f32_16x16x32_f16(a, bf8[(k0 * 4 + 0) * 64 + lane], acc0, 0, 0, 0);
            acc1 = __builtin_amdgcn_mfma_f32_16x16x32_f16(a, bf8[(k0 * 4 + 1) * 64 + lane], acc1, 0, 0, 0);
            acc2 = __builtin_amdgcn_mfma_f32_16x16x32_f16(a, bf8[(k0 * 4 + 2) * 64 + lane], acc2, 0, 0, 0);
            acc3 = __builtin_amdgcn_mfma_f32_16x16x32_f16(a, bf8[(k0 * 4 + 3) * 64 + lane], acc3, 0, 0, 0);
        }
        // C/D layout: col = lane&15, row = (lane>>4)*4 + reg   [HW-verified]
        #pragma unroll
        for (int r = 0; r < 4; ++r) {
            int row = (kgrp << 2) + r;
            csw[row * 68 +  0 + mrow] = acc0[r];
            csw[row * 68 + 16 + mrow] = acc1[r];
            csw[row * 68 + 32 + mrow] = acc2[r];
            csw[row * 68 + 48 + mrow] = acc3[r];
        }
        asm volatile("s_waitcnt lgkmcnt(0)" ::: "memory");   // wave-wide LDS RAW fence
        {
            int node = lane >> 2, cq = lane & 3;
            int n = n0 + node;
            if (n < N) {
                const float* src = &csw[node * 68 + (cq << 4)];
                float4 v0 = *(const float4*)(src);
                float4 v1 = *(const float4*)(src + 4);
                float4 v2 = *(const float4*)(src + 8);
                float4 v3 = *(const float4*)(src + 12);
                unsigned pk[8];
                pk[0] = f2h(v0.x) | (f2h(v0.y) << 16);
                pk[1] = f2h(v0.z) | (f2h(v0.w) << 16);
                pk[2] = f2h(v1.x) | (f2h(v1.y) << 16);
                pk[3] = f2h(v1.z) | (f2h(v1.w) << 16);
                pk[4] = f2h(v2.x) | (f2h(v2.y) << 16);
                pk[5] = f2h(v2.z) | (f2h(v2.w) << 16);
                pk[6] = f2h(v3.x) | (f2h(v3.y) << 16);
                pk[7] = f2h(v3.z) | (f2h(v3.w) << 16);
                char* dst = (char*)(hp + (size_t)n * 32) + (cq << 5);
                ((int4*)dst)[0] = *(int4*)&pk[0];
                ((int4*)dst)[1] = *(int4*)&pk[4];
            }
        }
        #pragma unroll
        for (int pr = 0; pr < 2; ++pr) {
            int node = (pr << 3) + (lane >> 3), head = lane & 7;
            int n = n0 + node;
            if (n < N) {
                float s = 0.f, d = 0.f;
                #pragma unroll
                for (int c = 0; c < 8; ++c) {
                    float v = csw[node * 68 + (head << 3) + c];
                    s = fmaf(v, attS[(head << 3) + c], s);
                    d = fmaf(v, attD[(head << 3) + c], d);
                }
                a_src1[n * 8 + head] = __float2half(s);
                a_dst1[n * 8 + head] = d;
            }
        }
    }
}

// ---------------- per-bucket counting sort -> esrc sorted by node + rowstart
__global__ __launch_bounds__(256) void bucket_sort_kernel(
    const unsigned* __restrict__ ebuf, const int* __restrict__ bucketBase,
    int* __restrict__ rowstart, int* __restrict__ esrc, int N)
{
    __shared__ int lhist[B_N];
    __shared__ int lstart[B_N];
    __shared__ int wsum1;
    int blk = blockIdx.x, t = threadIdx.x;
    int e0 = bucketBase[blk], e1 = bucketBase[blk + 1];
    if (t < B_N) lhist[t] = 0;
    __syncthreads();
    for (int k = e0 + t; k < e1; k += 256)
        atomicAdd(&lhist[ebuf[k] >> 25], 1);
    __syncthreads();
    int lane = t & 63;
    if (t < B_N) {                       // inclusive scan over 2 waves
        int s = lhist[t];
        for (int off = 1; off < 64; off <<= 1) {
            int u = __shfl_up(s, off);
            if (lane >= off) s += u;
        }
        lstart[t] = s;
        if (t == 63) wsum1 = s;
    }
    __syncthreads();
    if (t < B_N) {
        int s = lstart[t];
        if (t >= 64) s += wsum1;
        int excl = s - lhist[t];
        lstart[t] = excl;
        int n = blk * B_N + t;
        if (n < N) rowstart[n] = e0 + excl;
    }
    __syncthreads();
    if (t < B_N) lhist[t] = 0;           // reuse as rank cursor
    __syncthreads();
    for (int k = e0 + t; k < e1; k += 256) {
        unsigned pk = ebuf[k];
        int d = pk >> 25;
        int r = atomicAdd(&lhist[d], 1);
        esrc[e0 + lstart[d] + r] = (int)(pk & 0x1FFFFFF);
    }
}

// ---------------- Fused agg1 + gemm2. Block = 64 nodes (4 waves x 16-node tile).
// Agg: 2 nodes per wave-half; lane c2 owns channels {2c2,2c2+1}. Shared-exp:
// per 4-edge iter the 32 lanes compute the 32 (edge,head) exps once
// (lane -> edge=c2>>3, head=c2&7), then 4 shfl broadcasts. h2 -> wave-private
// LDS; then 2 MFMAs (K=64) + epilogue -> h2w fp16[N,16], a_src2[N], a_dst2[N].
__global__ __launch_bounds__(256) void agg1g2_kernel(
    const int* __restrict__ esrc, const int* __restrict__ rowstart,
    const float* __restrict__ hp, const __half* __restrict__ a_src1,
    const float* __restrict__ a_dst1, const float* __restrict__ b1,
    const float* __restrict__ W2, const float* __restrict__ att_s2,
    const float* __restrict__ att_d2, __half* __restrict__ h2w,
    float* __restrict__ a_src2, float* __restrict__ a_dst2, int N)
{
    __shared__ _Float16 w2frag[1024];          // 2 KB
    __shared__ _Float16 h2s[4][16][64];        // 8 KB, wave-private sections
    __shared__ float cs[4][16 * 20];           // 5 KB epilogue staging
    int tid = threadIdx.x;
    for (int idx = tid; idx < 1024; idx += 256) {
        int f = idx >> 9, l = (idx >> 3) & 63, j = idx & 7;
        int row = f * 32 + ((l >> 4) << 3) + j;   // same k-map as A-pack
        int col = l & 15;
        w2frag[idx] = (_Float16)W2[row * 16 + col];
    }
    __syncthreads();   // only barrier: w2frag ready

    int lane = tid & 63, wid = tid >> 6;
    int half = lane >> 5, c2 = lane & 31;
    int h = c2 >> 2;                 // fma-role head
    int ch = c2 & 7;                 // compute-role head
    int sbase = half * 32 + h;       // shfl source base: lane half*32 + j*8 + h
    float2 bb = *(const float2*)(b1 + 2 * c2);
    // gemm2-phase constants
    int mrow = lane & 15, kgrp = lane >> 4;
    const half8* w2bf8 = (const half8*)w2frag;
    float* csw = &cs[wid][0];
    int ech = (lane & 3) << 2;
    float as0 = att_s2[ech], as1 = att_s2[ech + 1], as2 = att_s2[ech + 2], as3 = att_s2[ech + 3];
    float ad0 = att_d2[ech], ad1 = att_d2[ech + 1], ad2 = att_d2[ech + 2], ad3 = att_d2[ech + 3];

    int ngroups = (N + 63) >> 6;
    for (int grp = blockIdx.x; grp < ngroups; grp += gridDim.x) {
        int wbase = (grp << 6) + (wid << 4);   // wave's 16 nodes
        // ---- agg phase: 8 subiters x 2 nodes ----
        for (int sub = 0; sub < 8; ++sub) {
            int nloc = (sub << 1) + half;
            int n = wbase + nloc;
            bool act = (n < N);
            int nn = act ? n : 0;
            int p = rowstart[nn], end = act ? rowstart[nn + 1] : 0;
            float ad_f = a_dst1[nn * 8 + h];    // fma-head dst logit
            float ad_c = a_dst1[nn * 8 + ch];   // compute-head dst logit
            float ax = 0.f, ay = 0.f, wsum = 0.f;
            for (; p + 3 < end; p += 4) {
                int s0 = esrc[p], s1 = esrc[p + 1], s2 = esrc[p + 2], s3 = esrc[p + 3];
                // shared-exp: this lane computes w for (edge c2>>3, head ch)
                int se = (c2 & 16) ? ((c2 & 8) ? s3 : s2) : ((c2 & 8) ? s1 : s0);
                float ac = __half2float(a_src1[se * 8 + ch]) + ad_c;
                ac = (ac > 0.f) ? ac : NEG * ac;
                float wl = __expf(ac);
                float w0 = __shfl(wl, sbase);
                float w1 = __shfl(wl, sbase + 8);
                float w2 = __shfl(wl, sbase + 16);
                float w3 = __shfl(wl, sbase + 24);
                __half2 q0 = ((const __half2*)(hp + (size_t)s0 * 32))[c2];
                __half2 q1 = ((const __half2*)(hp + (size_t)s1 * 32))[c2];
                __half2 q2 = ((const __half2*)(hp + (size_t)s2 * 32))[c2];
                __half2 q3 = ((const __half2*)(hp + (size_t)s3 * 32))[c2];
                ax = fmaf(w0, __low2float(q0), ax);  ay = fmaf(w0, __high2float(q0), ay);
                ax = fmaf(w1, __low2float(q1), ax);  ay = fmaf(w1, __high2float(q1), ay);
                ax = fmaf(w2, __low2float(q2), ax);  ay = fmaf(w2, __high2float(q2), ay);
                ax = fmaf(w3, __low2float(q3), ax);  ay = fmaf(w3, __high2float(q3), ay);
                wsum += (w0 + w1) + (w2 + w3);
            }
            for (; p < end; ++p) {
                int s0 = esrc[p];
                float a0 = __half2float(a_src1[s0 * 8 + h]) + ad_f;
                __half2 q0 = ((const __half2*)(hp + (size_t)s0 * 32))[c2];
                a0 = (a0 > 0.f) ? a0 : NEG * a0;
                float w0 = __expf(a0);
                ax = fmaf(w0, __low2float(q0), ax);
                ay = fmaf(w0, __high2float(q0), ay);
                wsum += w0;
            }
            float inv = 1.f / (wsum + GAT_EPS);
            float vx = fmaf(ax, inv, bb.x);
            float vy = fmaf(ay, inv, bb.y);
            vx = (act && vx > 0.f) ? vx : 0.f;
            vy = (act && vy > 0.f) ? vy : 0.f;
            ((__half2*)&h2s[wid][nloc][0])[c2] =
                __halves2half2(__float2half(vx), __float2half(vy));
        }
        // ---- gemm2 phase (wave-private LDS; no cross-wave sync) ----
        asm volatile("s_waitcnt lgkmcnt(0)" ::: "memory");
        f32x4 acc = {0, 0, 0, 0};
        const half8* ar = (const half8*)&h2s[wid][mrow][0];
        acc = __builtin_amdgcn_mfma_f32_16x16x32_f16(ar[kgrp], w2bf8[lane], acc, 0, 0, 0);
        acc = __builtin_amdgcn_mfma_f32_16x16x32_f16(ar[4 + kgrp], w2bf8[64 + lane], acc, 0, 0, 0);
        #pragma unroll
        for (int r = 0; r < 4; ++r)
            csw[((kgrp << 2) + r) * 20 + mrow] = acc[r];
        asm volatile("s_waitcnt lgkmcnt(0)" ::: "memory");
        int node = lane >> 2;
        int n = wbase + node;
        if (n < N) {
            float4 v = *(const float4*)&csw[node * 20 + ech];
            unsigned pk0 = f2h(v.x) | (f2h(v.y) << 16);
            unsigned pk1 = f2h(v.z) | (f2h(v.w) << 16);
            *(int2*)((char*)(h2w + (size_t)n * 16) + (ech << 1)) = make_int2((int)pk0, (int)pk1);
            float s = fmaf(v.x, as0, fmaf(v.y, as1, fmaf(v.z, as2, v.w * as3)));
            float d = fmaf(v.x, ad0, fmaf(v.y, ad1, fmaf(v.z, ad2, v.w * ad3)));
            s += __shfl_xor(s, 1); d += __shfl_xor(d, 1);
            s += __shfl_xor(s, 2); d += __shfl_xor(d, 2);
            if ((lane & 3) == 0) { a_src2[n] = s; a_dst2[n] = d; }
        }
    }
}

// ---------------- Layer 2 aggregation: 8 nodes per wave (8 lanes each), 4-deep.
__global__ __launch_bounds__(256) void agg2_kernel(
    const int* __restrict__ esrc, const int* __restrict__ rowstart,
    const __half* __restrict__ h2w, const float* __restrict__ a_src2,
    const float* __restrict__ a_dst2, const float* __restrict__ b2,
    float* __restrict__ out, int N)
{
    int wslot = (blockIdx.x * 256 + threadIdx.x) >> 6;
    int nw = (gridDim.x * 256) >> 6;
    int lane = threadIdx.x & 63;
    int oct = lane >> 3, c2 = lane & 7;
    for (int base = wslot * 8; base < N; base += nw * 8) {
        int n = base + oct;
        bool act = (n < N);
        int nn = act ? n : 0;
        int p = rowstart[nn], end = act ? rowstart[nn + 1] : 0;
        float ad = a_dst2[nn];
        float ax = 0.f, ay = 0.f, wsum = 0.f;
        for (; p + 3 < end; p += 4) {
            int s0 = esrc[p], s1 = esrc[p + 1], s2 = esrc[p + 2], s3 = esrc[p + 3];
            float a0 = a_src2[s0] + ad;
            float a1 = a_src2[s1] + ad;
            float a2 = a_src2[s2] + ad;
            float a3 = a_src2[s3] + ad;
            __half2 q0 = ((const __half2*)(h2w + (size_t)s0 * 16))[c2];
            __half2 q1 = ((const __half2*)(h2w + (size_t)s1 * 16))[c2];
            __half2 q2 = ((const __half2*)(h2w + (size_t)s2 * 16))[c2];
            __half2 q3 = ((const __half2*)(h2w + (size_t)s3 * 16))[c2];
            a0 = (a0 > 0.f) ? a0 : NEG * a0;
            a1 = (a1 > 0.f) ? a1 : NEG * a1;
            a2 = (a2 > 0.f) ? a2 : NEG * a2;
            a3 = (a3 > 0.f) ? a3 : NEG * a3;
            float w0 = __expf(a0), w1 = __expf(a1), w2 = __expf(a2), w3 = __expf(a3);
            ax = fmaf(w0, __low2float(q0), ax);  ay = fmaf(w0, __high2float(q0), ay);
            ax = fmaf(w1, __low2float(q1), ax);  ay = fmaf(w1, __high2float(q1), ay);
            ax = fmaf(w2, __low2float(q2), ax);  ay = fmaf(w2, __high2float(q2), ay);
            ax = fmaf(w3, __low2float(q3), ax);  ay = fmaf(w3, __high2float(q3), ay);
            wsum += (w0 + w1) + (w2 + w3);
        }
        for (; p < end; ++p) {
            int s0 = esrc[p];
            float a0 = a_src2[s0] + ad;
            __half2 q0 = ((const __half2*)(h2w + (size_t)s0 * 16))[c2];
            a0 = (a0 > 0.f) ? a0 : NEG * a0;
            float w0 = __expf(a0);
            ax = fmaf(w0, __low2float(q0), ax);
            ay = fmaf(w0, __high2float(q0), ay);
            wsum += w0;
        }
        if (act) {
            float inv = 1.f / (wsum + GAT_EPS);
            float2 bb = *(const float2*)(b2 + 2 * c2);
            float2 o;
            o.x = fmaf(ax, inv, bb.x);
            o.y = fmaf(ay, inv, bb.y);
            o.x = o.x > 0.f ? o.x : 0.f;
            o.y = o.y > 0.f ? o.y : 0.f;
            ((float2*)(out + (size_t)n * 16))[c2] = o;
        }
    }
}

extern "C" void kernel_launch(void* const* d_in, const int* in_sizes, int n_in,
                              void* d_out, int out_size, void* d_ws, size_t ws_size,
                              hipStream_t stream)
{
    const float* x      = (const float*)d_in[0];
    const int*   ei     = (const int*)  d_in[1];   // [2,E] int32
    const float* W1     = (const float*)d_in[2];
    const float* att_s1 = (const float*)d_in[3];
    const float* att_d1 = (const float*)d_in[4];
    const float* b1     = (const float*)d_in[5];
    const float* W2     = (const float*)d_in[6];
    const float* att_s2 = (const float*)d_in[7];
    const float* att_d2 = (const float*)d_in[8];
    const float* b2     = (const float*)d_in[9];
    float* out = (float*)d_out;

    int N = in_sizes[0] / IN_C;
    int E = in_sizes[1] / 2;
    int Etot = E + N;
    int NB = (N + B_N - 1) / B_N;      // 782 for N=100000 (<= NB_MAX)

    // workspace: floats, then ints (h2 buffer no longer needed — LDS-resident)
    float* ws = (float*)d_ws;
    float*  hp      = ws;                               // N*32 (fp16 h, 128 B rows)
    __half* a_src1  = (__half*)(hp + (size_t)N * 32);   // N*8 halves = N*4 floats
    float*  a_dst1  = (float*)a_src1 + (size_t)N * 4;   // N*8
    __half* h2w     = (__half*)(a_dst1 + (size_t)N * 8);// N*16 halves = N*8 floats
    float*  a_src2  = (float*)h2w + (size_t)N * 8;      // N
    float*  a_dst2  = a_src2 + (size_t)N;               // N
    int* rowstart   = (int*)(a_dst2 + (size_t)N);       // N+1
    int* bucketCnt  = rowstart   + (N + 1);             // NB_MAX
    int* bucketBase = bucketCnt  + NB_MAX;              // NB_MAX+1
    int* bucketCur  = bucketBase + NB_MAX + 1;          // NB_MAX
    int* esrc       = bucketCur  + NB_MAX;              // Etot
    unsigned* ebuf  = (unsigned*)(esrc + Etot);         // Etot

    int egrid = (Etot + TILE - 1) / TILE;

    hipMemsetAsync(bucketCnt, 0, NB_MAX * sizeof(int), stream);
    bucket_count_kernel<<<egrid, 256, 0, stream>>>(ei, bucketCnt, E, Etot, NB);
    bucket_scan_kernel<<<1, 256, 0, stream>>>(bucketCnt, bucketBase, bucketCur,
                                              rowstart, NB, N, Etot);
    // K2: partition (blocks [0,egrid)) + gemm1 (blocks [egrid, egrid+GEMM_BLKS))
    k2_kernel<<<egrid + GEMM_BLKS, 256, 0, stream>>>(
        x, W1, att_s1, att_d1, hp, a_src1, a_dst1, ei, bucketCur, ebuf,
        E, Etot, NB, N, egrid);
    bucket_sort_kernel<<<NB, 256, 0, stream>>>(ebuf, bucketBase, rowstart, esrc, N);

    // fused agg1 + gemm2
    {
        int ngroups = (N + 63) >> 6;   // 1563
        agg1g2_kernel<<<ngroups, 256, 0, stream>>>(
            esrc, rowstart, hp, a_src1, a_dst1, b1,
            W2, att_s2, att_d2, h2w, a_src2, a_dst2, N);
    }
    agg2_kernel<<<1024, 256, 0, stream>>>(esrc, rowstart, h2w, a_src2, a_dst2, b2, out, N);
}